// Round 8
// baseline (1502.037 us; speedup 1.0000x reference)
//
#include <hip/hip_runtime.h>
#include <hip/hip_bf16.h>

#define DD 128
#define LL 8
#define MM 32768
#define NN (LL*MM)
#define GG 5
#define FF 2
#define SORT_STRIDE 33408   // 32768 + headroom (>= 5*31 pad)

typedef __attribute__((ext_vector_type(8))) short short8;
typedef __attribute__((ext_vector_type(4))) short short4v;
typedef __attribute__((ext_vector_type(4))) float f32x4;

#define MFMA16(a,b,c) __builtin_amdgcn_mfma_f32_16x16x32_bf16((a),(b),(c),0,0,0)

__device__ __forceinline__ short f2bf(float x){
  __hip_bfloat16 h = __float2bfloat16(x);
  return *reinterpret_cast<short*>(&h);
}

__device__ __forceinline__ short8 pack8(f32x4 a, f32x4 b){
  short8 r;
  r[0]=f2bf(a[0]); r[1]=f2bf(a[1]); r[2]=f2bf(a[2]); r[3]=f2bf(a[3]);
  r[4]=f2bf(b[0]); r[5]=f2bf(b[1]); r[6]=f2bf(b[2]); r[7]=f2bf(b[3]);
  return r;
}

// Device-scope grid barrier: monotonic counter, zeroed each replay by a
// hipMemsetAsync node. Requires all gridDim.x blocks co-resident (grid size
// derived from hipOccupancyMaxActiveBlocksPerMultiprocessor at launch).
__device__ __forceinline__ void gbar(int* bar, int target){
  __syncthreads();
  if (threadIdx.x == 0){
    __threadfence();
    atomicAdd(bar, 1);
    while (__hip_atomic_load(bar, __ATOMIC_ACQUIRE, __HIP_MEMORY_SCOPE_AGENT) < target)
      __builtin_amdgcn_s_sleep(8);
    __threadfence();
  }
  __syncthreads();
}

// =================== THE mega kernel: everything, 9 grid barriers ==========
__global__ __launch_bounds__(256,4) void mega_kernel(
    const float* __restrict__ s, const float* __restrict__ t,
    const int* __restrict__ gate, const int* __restrict__ fanin,
    const float* __restrict__ hs_W, const float* __restrict__ hs_b,
    const float* __restrict__ W1, const float* __restrict__ b1,
    const float* __restrict__ W2, const float* __restrict__ b2,
    const float* __restrict__ W3, const float* __restrict__ b3,
    const float* __restrict__ Wi, const float* __restrict__ bi,
    const float* __restrict__ bh,
    float* __restrict__ hs, float* __restrict__ hf,
    short* __restrict__ hsWt, short* __restrict__ W1t, short* __restrict__ W2t,
    short* __restrict__ W3t, short* __restrict__ Wit,
    short* __restrict__ hs_sh, short* __restrict__ hf_sh,
    int* __restrict__ cnt, int* __restrict__ cur, int* __restrict__ off,
    int* __restrict__ pend, int* __restrict__ pad_end,
    int* __restrict__ sorted, int* __restrict__ bar)
{
  __shared__ __align__(16) short Xs[16384];
  __shared__ int nodebuf[32];
  __shared__ int srcbuf[64];
  __shared__ int ginfo;

  const int blk = blockIdx.x, NB = gridDim.x;
  const int tid = threadIdx.x, lane = tid & 63, w = tid >> 6;
  const int l15 = lane & 15, lq = lane >> 4;
  f32x4 zf = {0.f,0.f,0.f,0.f};

  // ---------------- Phase A: weight prep + gate count ----------------
  for (int u = blk*256 + tid; u < 75776; u += NB*256){
    const float* src; short* dst; int ldw;
    if (u < 4096){                                   // hsWt: ct8 kc8
      int i=u, ct=i>>9, kc=(i>>6)&7, ln=i&63;
      src = hs_W + (size_t)(kc*32 + 8*(ln>>4))*128 + ct*16 + (ln&15);
      dst = hsWt + (size_t)i*8; ldw=128;
    } else if (u < 24576){                           // W1t: 5 x (ct8 kc8)
      int v=u-4096, g=v>>12, i=v&4095, ct=i>>9, kc=(i>>6)&7, ln=i&63;
      src = W1 + (size_t)g*32768 + (size_t)(kc*32 + 8*(ln>>4))*128 + ct*16 + (ln&15);
      dst = W1t + (size_t)g*32768 + i*8; ldw=128;
    } else if (u < 34816){                           // W2t: 5 x (ct8 kc4)
      int v=u-24576, g=v>>11, i=v&2047, ct=i>>8, kc=(i>>6)&3, ln=i&63;
      src = W2 + (size_t)g*16384 + (size_t)(kc*32 + 8*(ln>>4))*128 + ct*16 + (ln&15);
      dst = W2t + (size_t)g*16384 + i*8; ldw=128;
    } else if (u < 45056){                           // W3t: 5 x (ct8 kc4)
      int v=u-34816, g=v>>11, i=v&2047, ct=i>>8, kc=(i>>6)&3, ln=i&63;
      src = W3 + (size_t)g*16384 + (size_t)(kc*32 + 8*(ln>>4))*128 + ct*16 + (ln&15);
      dst = W3t + (size_t)g*16384 + i*8; ldw=128;
    } else {                                         // Wit: 5 x (ct24 kc4)
      int v=u-45056, g=v/6144, i=v%6144, ct=i>>8, kc=(i>>6)&3, ln=i&63;
      src = Wi + (size_t)g*49152 + (size_t)(kc*32 + 8*(ln>>4))*384 + ct*16 + (ln&15);
      dst = Wit + (size_t)g*49152 + i*8; ldw=384;
    }
    short8 o;
#pragma unroll
    for (int j=0;j<8;++j) o[j] = f2bf(src[(size_t)j*ldw]);
    *(short8*)dst = o;
  }
  // count: 896 chunks of 256 (chunk fully inside one level)
  for (int c0 = blk; c0 < 896; c0 += NB){
    int* lc = (int*)Xs;
    __syncthreads();
    if (tid < GG) lc[tid] = 0;
    __syncthreads();
    int idx = c0*256 + tid;
    int li = idx >> 15, m = idx & 32767;
    int g = gate[(li+1)*MM + m];
    atomicAdd(&lc[g], 1);
    __syncthreads();
    if (tid < GG && lc[tid] > 0) atomicAdd(&cnt[li*GG + tid], lc[tid]);
  }
  gbar(bar, NB*1);

  // ---------------- Phase B: offsets + pad fill (blocks 0..6) --------
  if (blk < LL-1){
    int* lds_i = (int*)Xs;
    if (tid == 0){
      int l = blk, o = 0;
      for (int g2 = 0; g2 < GG; ++g2){
        off[l*GG+g2] = o;
        int c = cnt[l*GG+g2];
        pend[l*GG+g2] = o + c;
        lds_i[g2] = o + c;
        o += ((c + 31) >> 5) << 5;          // pad bucket to 32
        lds_i[8+g2] = o;
      }
      pad_end[l] = o;
    }
    __syncthreads();
    for (int b2 = 0; b2 < GG; ++b2)
      for (int i = lds_i[b2] + tid; i < lds_i[8+b2]; i += 256)
        sorted[blk*SORT_STRIDE + i] = -1;
  }
  gbar(bar, NB*2);

  // ---------------- Phase C: scatter + hs + level-0 hf zero ----------
  for (int c0 = blk; c0 < 896; c0 += NB){
    int* lc = (int*)Xs; int* base = lc + 8;
    __syncthreads();
    if (tid < GG) lc[tid] = 0;
    __syncthreads();
    int idx = c0*256 + tid;
    int li = idx >> 15, m = idx & 32767;
    int g = gate[(li+1)*MM + m];
    int p = atomicAdd(&lc[g], 1);
    __syncthreads();
    if (tid < GG) base[tid] = atomicAdd(&cur[li*GG + tid], lc[tid]);
    __syncthreads();
    sorted[li*SORT_STRIDE + off[li*GG+g] + base[g] + p] = m;
  }
  // hs items: 4096 x 64 rows
  for (int it = blk; it < 4096; it += NB){
    const int row0 = it*64;
    __syncthreads();                       // protect prior item's Xs reads
    {
      const int r = tid>>2, p = tid&3;
      const float* srow = s + (size_t)(row0+r)*DD;
      const float* trow = t + (size_t)(row0+r)*DD;
      const int rf = r>>4, rl = r&15;
#pragma unroll
      for (int i=0;i<8;++i){
        int u = p + 4*i;
        const float* pp = (u<16) ? (srow + 8*u) : (trow + 8*(u-16));
        short8 v = pack8(*(const f32x4*)pp, *(const f32x4*)(pp+4));
        *(short8*)(Xs + ((rf*8+(u>>2))*64 + (u&3)*16 + rl)*8) = v;
      }
    }
    if (row0 < MM){                        // level-0 hf zero-fill
      short8 zs8 = {0,0,0,0,0,0,0,0};
      const size_t basei = (size_t)row0*DD;
      for (int i=tid; i<2048; i+=256) *(f32x4*)(hf + basei + i*4) = zf;
      for (int i=tid; i<1024; i+=256) *(short8*)(hf_sh + basei + i*8) = zs8;
    }
    __syncthreads();

    f32x4 acc[4][2];
#pragma unroll
    for (int rr=0;rr<4;++rr){ acc[rr][0]=zf; acc[rr][1]=zf; }
    const short* Ab = hsWt + lane*8;
#pragma unroll
    for (int kc=0;kc<8;++kc){
      short8 a0 = *(const short8*)(Ab + (16*w + kc)*512);
      short8 a1 = *(const short8*)(Ab + (16*w + 8 + kc)*512);
#pragma unroll
      for (int rr=0;rr<4;++rr){
        short8 bx = *(const short8*)(Xs + ((rr*8 + kc)*64 + lane)*8);
        acc[rr][0] = MFMA16(a0, bx, acc[rr][0]);
        acc[rr][1] = MFMA16(a1, bx, acc[rr][1]);
      }
    }
    f32x4 bv0 = *(const f32x4*)(hs_b + 32*w + 4*lq);
    f32x4 bv1 = *(const f32x4*)(hs_b + 32*w + 16 + 4*lq);
#pragma unroll
    for (int rr=0;rr<4;++rr){
      int row = row0 + rr*16 + l15;
#pragma unroll
      for (int q=0;q<2;++q){
        f32x4 bv = q ? bv1 : bv0;
        int col = 32*w + 16*q + 4*lq;
        f32x4 o; short4v pk;
#pragma unroll
        for (int j=0;j<4;++j){ o[j] = acc[rr][q][j] + bv[j]; pk[j] = f2bf(o[j]); }
        *(f32x4*)(hs + (size_t)row*DD + col) = o;
        *(short4v*)(hs_sh + (size_t)row*DD + col) = pk;
      }
    }
  }
  gbar(bar, NB*3);

  // ---------------- Phases D..J: levels 1..7 -------------------------
  for (int lvl = 1; lvl < LL; ++lvl){
    const int li = lvl-1;
    const int pe = pad_end[li];
    for (int it = blk; it*32 < pe; it += NB){
      const int pos0 = it*32;
      __syncthreads();                     // protect prior item's LDS
      if (tid==0){
        int g=-1;
        for (int q=0;q<GG;++q)
          if (pos0>=off[li*GG+q] && pos0<pend[li*GG+q]){ g=q; break; }
        ginfo=g;
      }
      if (tid<32) nodebuf[tid] = sorted[li*SORT_STRIDE + pos0 + tid];
      if (tid<64){
        int mg = sorted[li*SORT_STRIDE + pos0 + (tid>>1)];
        srcbuf[tid] = (mg>=0) ? li*MM + fanin[((size_t)li*MM+mg)*FF + (tid&1)] : 0;
      }
      __syncthreads();                                  // B0
      const int g = ginfo;
      if (g >= 0){                                      // block-uniform skip
        // gather X rows into fragment layout
        {
          const int r = tid>>2, p = tid&3;
          const int src = srcbuf[r];
          const short* hsrow = hs_sh + (size_t)src*DD;
          const short* hfrow = hf_sh + (size_t)src*DD;
          const int rf = r>>4, rl = r&15;
#pragma unroll
          for (int i=0;i<8;++i){
            int u = p + 4*i;
            short8 v = *(const short8*)((u<16) ? (hsrow + 8*u) : (hfrow + 8*(u-16)));
            *(short8*)(Xs + ((rf*8+(u>>2))*64 + (u&3)*16 + rl)*8) = v;
          }
        }
        __syncthreads();                                // B1

        // ---- GEMM1: K=256 ----
        f32x4 acc[4][2];
#pragma unroll
        for (int rr=0;rr<4;++rr){ acc[rr][0]=zf; acc[rr][1]=zf; }
        const short* A1 = W1t + (size_t)g*32768 + lane*8;
#pragma unroll
        for (int kc=0;kc<8;++kc){
          short8 a0 = *(const short8*)(A1 + (16*w + kc)*512);
          short8 a1 = *(const short8*)(A1 + (16*w + 8 + kc)*512);
#pragma unroll
          for (int rr=0;rr<4;++rr){
            short8 bx = *(const short8*)(Xs + ((rr*8 + kc)*64 + lane)*8);
            acc[rr][0] = MFMA16(a0, bx, acc[rr][0]);
            acc[rr][1] = MFMA16(a1, bx, acc[rr][1]);
          }
        }
        __syncthreads();                                // B2
        {
          f32x4 bv0 = *(const f32x4*)(b1 + g*DD + 32*w + 4*lq);
          f32x4 bv1 = *(const f32x4*)(b1 + g*DD + 32*w + 16 + 4*lq);
#pragma unroll
          for (int rr=0;rr<4;++rr){
#pragma unroll
            for (int q=0;q<2;++q){
              f32x4 bv = q ? bv1 : bv0;
              short4v pk;
#pragma unroll
              for (int j=0;j<4;++j) pk[j] = f2bf(fmaxf(acc[rr][q][j] + bv[j], 0.f));
              *(short4v*)(Xs + ((rr*4 + w)*64 + (2*q + (lq>>1))*16 + l15)*8 + 4*(lq&1)) = pk;
            }
          }
        }
        __syncthreads();                                // B3

        // ---- GEMM2: K=128 ----
        f32x4 acc2[4][2];
#pragma unroll
        for (int rr=0;rr<4;++rr){ acc2[rr][0]=zf; acc2[rr][1]=zf; }
        const short* A2 = W2t + (size_t)g*16384 + lane*8;
#pragma unroll
        for (int kc=0;kc<4;++kc){
          short8 a0 = *(const short8*)(A2 + (8*w + kc)*512);
          short8 a1 = *(const short8*)(A2 + (8*w + 4 + kc)*512);
#pragma unroll
          for (int rr=0;rr<4;++rr){
            short8 bx = *(const short8*)(Xs + ((rr*4 + kc)*64 + lane)*8);
            acc2[rr][0] = MFMA16(a0, bx, acc2[rr][0]);
            acc2[rr][1] = MFMA16(a1, bx, acc2[rr][1]);
          }
        }
        {
          f32x4 bv0 = *(const f32x4*)(b2 + g*DD + 32*w + 4*lq);
          f32x4 bv1 = *(const f32x4*)(b2 + g*DD + 32*w + 16 + 4*lq);
#pragma unroll
          for (int rr=0;rr<4;++rr){
#pragma unroll
            for (int q=0;q<2;++q){
              f32x4 bv = q ? bv1 : bv0;
              short4v pk;
#pragma unroll
              for (int j=0;j<4;++j) pk[j] = f2bf(fmaxf(acc2[rr][q][j] + bv[j], 0.f));
              *(short4v*)(Xs + 8192 + ((rr*4 + w)*64 + (2*q + (lq>>1))*16 + l15)*8 + 4*(lq&1)) = pk;
            }
          }
        }
        __syncthreads();                                // B4

        // ---- GEMM3: K=128 ----
        f32x4 acc3[4][2];
#pragma unroll
        for (int rr=0;rr<4;++rr){ acc3[rr][0]=zf; acc3[rr][1]=zf; }
        const short* A3 = W3t + (size_t)g*16384 + lane*8;
#pragma unroll
        for (int kc=0;kc<4;++kc){
          short8 a0 = *(const short8*)(A3 + (8*w + kc)*512);
          short8 a1 = *(const short8*)(A3 + (8*w + 4 + kc)*512);
#pragma unroll
          for (int rr=0;rr<4;++rr){
            short8 bx = *(const short8*)(Xs + 8192 + ((rr*4 + kc)*64 + lane)*8);
            acc3[rr][0] = MFMA16(a0, bx, acc3[rr][0]);
            acc3[rr][1] = MFMA16(a1, bx, acc3[rr][1]);
          }
        }
        // pair-sum over F -> msg into Xs[0:4096)
        {
          f32x4 bv0 = *(const f32x4*)(b3 + g*DD + 32*w + 4*lq);
          f32x4 bv1 = *(const f32x4*)(b3 + g*DD + 32*w + 16 + 4*lq);
#pragma unroll
          for (int rr=0;rr<4;++rr){
#pragma unroll
            for (int q=0;q<2;++q){
              f32x4 bv = q ? bv1 : bv0;
              f32x4 mv;
#pragma unroll
              for (int j=0;j<4;++j){
                float v = acc3[rr][q][j];
                mv[j] = v + __shfl_xor(v, 1) + 2.f*bv[j];
              }
              if ((l15 & 1) == 0){
                int n = rr*8 + (l15>>1);               // node 0..31
                short4v pk;
#pragma unroll
                for (int j=0;j<4;++j) pk[j] = f2bf(mv[j]);
                *(short4v*)(Xs + (((n>>4)*4 + w)*64 + (2*q + (lq>>1))*16 + (n&15))*8 + 4*(lq&1)) = pk;
              }
            }
          }
        }
        __syncthreads();                                // B5

        // ---- GRU (2 q-passes) ----
        const short* AW = Wit + (size_t)g*49152 + lane*8;
        const int lo = lvl*MM;
#pragma unroll
        for (int q=0;q<2;++q){
          f32x4 gr[2], gz[2], gn[2];
          gr[0]=zf; gr[1]=zf; gz[0]=zf; gz[1]=zf; gn[0]=zf; gn[1]=zf;
#pragma unroll
          for (int kc=0;kc<4;++kc){
            int cti = ((2*w + q)*4 + kc)*512;
            short8 aR = *(const short8*)(AW + cti);
            short8 aZ = *(const short8*)(AW + 16384 + cti);
            short8 aN = *(const short8*)(AW + 32768 + cti);
#pragma unroll
            for (int rfm=0;rfm<2;++rfm){
              short8 bm = *(const short8*)(Xs + ((rfm*4 + kc)*64 + lane)*8);
              gr[rfm] = MFMA16(aR, bm, gr[rfm]);
              gz[rfm] = MFMA16(aZ, bm, gz[rfm]);
              gn[rfm] = MFMA16(aN, bm, gn[rfm]);
            }
          }
          int col = 32*w + 16*q + 4*lq;
          f32x4 biR = *(const f32x4*)(bi + g*384 + col);
          f32x4 biZ = *(const f32x4*)(bi + g*384 + 128 + col);
          f32x4 biN = *(const f32x4*)(bi + g*384 + 256 + col);
          f32x4 bhR = *(const f32x4*)(bh + g*384 + col);
          f32x4 bhZ = *(const f32x4*)(bh + g*384 + 128 + col);
          f32x4 bhN = *(const f32x4*)(bh + g*384 + 256 + col);
#pragma unroll
          for (int rfm=0;rfm<2;++rfm){
            int m = nodebuf[rfm*16 + l15];
            if (m < 0) continue;
            f32x4 o; short4v pk;
#pragma unroll
            for (int j=0;j<4;++j){
              float xr = gr[rfm][j] + biR[j] + bhR[j];
              float xz = gz[rfm][j] + biZ[j] + bhZ[j];
              float r_ = 1.f/(1.f + __expf(-xr));
              float z_ = 1.f/(1.f + __expf(-xz));
              float xn = gn[rfm][j] + biN[j] + r_*bhN[j];
              float n_ = 2.f/(1.f + __expf(-2.f*xn)) - 1.f;
              o[j] = (1.f - z_)*n_;
              pk[j] = f2bf(o[j]);
            }
            *(f32x4*)(hf + (size_t)(lo + m)*DD + col) = o;
            *(short4v*)(hf_sh + (size_t)(lo + m)*DD + col) = pk;
          }
        }
      } // g >= 0
    } // items
    if (lvl < LL-1) gbar(bar, NB*(3+lvl));
  } // levels
}

extern "C" void kernel_launch(void* const* d_in, const int* in_sizes, int n_in,
                              void* d_out, int out_size, void* d_ws, size_t ws_size,
                              hipStream_t stream)
{
  const float* s    = (const float*)d_in[0];
  const float* t    = (const float*)d_in[1];
  const int*   gate = (const int*)d_in[2];
  const int*   fanin= (const int*)d_in[3];
  const float* hs_W = (const float*)d_in[4];
  const float* hs_b = (const float*)d_in[5];
  const float* W1   = (const float*)d_in[6];
  const float* b1   = (const float*)d_in[7];
  const float* W2   = (const float*)d_in[8];
  const float* b2   = (const float*)d_in[9];
  const float* W3   = (const float*)d_in[10];
  const float* b3   = (const float*)d_in[11];
  const float* Wi   = (const float*)d_in[12];
  // d_in[13] = gru_Wh: unused (hidden state is exactly zero)
  const float* bi   = (const float*)d_in[14];
  const float* bh   = (const float*)d_in[15];

  float* hs = (float*)d_out;
  float* hf = hs + (size_t)NN*DD;

  int* cnt     = (int*)d_ws;       // [7][5]
  int* cur     = cnt + 35;         // [7][5]
  int* off     = cnt + 70;         // [7][5]
  int* pendv   = cnt + 105;        // [7][5]
  int* pad_end = cnt + 140;        // [7]
  int* bar     = cnt + 160;        // barrier counter (own line)
  int* sorted  = cnt + 256;        // 7*SORT_STRIDE ints, < 1 MB

  short* wbase = (short*)((char*)d_ws + (1<<20));
  short* hsWt = wbase;             // 4096*8
  short* W1t  = wbase + 32768;     // 5*32768
  short* W2t  = wbase + 196608;    // 5*16384
  short* W3t  = wbase + 278528;    // 5*16384
  short* Wit  = wbase + 360448;    // 5*49152

  short* hs_sh = (short*)((char*)d_ws + (size_t)(8<<20));   // [N][128] bf16
  short* hf_sh = hs_sh + (size_t)NN*DD;                      // [N][128] bf16

  // co-residency-safe grid size (host-side query; graph-capture legal)
  int nper = 0;
  hipOccupancyMaxActiveBlocksPerMultiprocessor(&nper, mega_kernel, 256, 0);
  if (nper < 1) nper = 1;
  int NBLK = nper * 256;           // 256 CUs on MI355X
  if (NBLK > 1024) NBLK = 1024;

  hipMemsetAsync(d_ws, 0, 1024, stream);   // cnt/cur/off/pend/pad_end/bar = 0
  mega_kernel<<<NBLK, 256, 0, stream>>>(
      s, t, gate, fanin, hs_W, hs_b, W1, b1, W2, b2, W3, b3, Wi, bi, bh,
      hs, hf, hsWt, W1t, W2t, W3t, Wit, hs_sh, hf_sh,
      cnt, cur, off, pendv, pad_end, sorted, bar);
}

// Round 9
// 905.712 us; speedup vs baseline: 1.6584x; 1.6584x over previous
//
#include <hip/hip_runtime.h>
#include <hip/hip_bf16.h>

#define DD 128
#define LL 8
#define MM 32768
#define NN (LL*MM)
#define GG 5
#define FF 2
#define SORT_STRIDE 33408   // 32768 + headroom (>= 5*31 pad)

typedef __attribute__((ext_vector_type(8))) short short8;
typedef __attribute__((ext_vector_type(4))) short short4v;
typedef __attribute__((ext_vector_type(4))) float f32x4;

#define MFMA16(a,b,c) __builtin_amdgcn_mfma_f32_16x16x32_bf16((a),(b),(c),0,0,0)

__device__ __forceinline__ short f2bf(float x){
  __hip_bfloat16 h = __float2bfloat16(x);
  return *reinterpret_cast<short*>(&h);
}

__device__ __forceinline__ short8 pack8(f32x4 a, f32x4 b){
  short8 r;
  r[0]=f2bf(a[0]); r[1]=f2bf(a[1]); r[2]=f2bf(a[2]); r[3]=f2bf(a[3]);
  r[4]=f2bf(b[0]); r[5]=f2bf(b[1]); r[6]=f2bf(b[2]); r[7]=f2bf(b[3]);
  return r;
}

// Device-scope grid barrier. CRITICAL (R8 lesson): poll with RELAXED loads —
// an agent-scope ACQUIRE in the spin loop invalidates the per-XCD L2 every
// iteration, destroying L2 for all still-running blocks (1502us vs 405us).
// Exactly one release (L2 writeback) on arrival + one acquire fence on exit.
__device__ __forceinline__ void gbar(int* bar, int target){
  __syncthreads();
  if (threadIdx.x == 0){
    __hip_atomic_fetch_add(bar, 1, __ATOMIC_RELEASE, __HIP_MEMORY_SCOPE_AGENT);
    while (__hip_atomic_load(bar, __ATOMIC_RELAXED, __HIP_MEMORY_SCOPE_AGENT) < target)
      __builtin_amdgcn_s_sleep(16);
    __builtin_amdgcn_fence(__ATOMIC_ACQUIRE, "agent");
  }
  __syncthreads();
}

// =================== THE mega kernel: everything, 9 grid barriers ==========
__global__ __launch_bounds__(256,4) void mega_kernel(
    const float* __restrict__ s, const float* __restrict__ t,
    const int* __restrict__ gate, const int* __restrict__ fanin,
    const float* __restrict__ hs_W, const float* __restrict__ hs_b,
    const float* __restrict__ W1, const float* __restrict__ b1,
    const float* __restrict__ W2, const float* __restrict__ b2,
    const float* __restrict__ W3, const float* __restrict__ b3,
    const float* __restrict__ Wi, const float* __restrict__ bi,
    const float* __restrict__ bh,
    float* __restrict__ hs, float* __restrict__ hf,
    short* __restrict__ hsWt, short* __restrict__ W1t, short* __restrict__ W2t,
    short* __restrict__ W3t, short* __restrict__ Wit,
    short* __restrict__ hs_sh, short* __restrict__ hf_sh,
    int* __restrict__ cnt, int* __restrict__ cur, int* __restrict__ off,
    int* __restrict__ pend, int* __restrict__ pad_end,
    int* __restrict__ sorted, int* __restrict__ bar)
{
  __shared__ __align__(16) short Xs[16384];
  __shared__ int nodebuf[32];
  __shared__ int srcbuf[64];
  __shared__ int ginfo;

  const int blk = blockIdx.x, NB = gridDim.x;
  const int tid = threadIdx.x, lane = tid & 63, w = tid >> 6;
  const int l15 = lane & 15, lq = lane >> 4;
  f32x4 zf = {0.f,0.f,0.f,0.f};

  // ---------------- Phase A: weight prep + gate count ----------------
  for (int u = blk*256 + tid; u < 75776; u += NB*256){
    const float* src; short* dst; int ldw;
    if (u < 4096){                                   // hsWt: ct8 kc8
      int i=u, ct=i>>9, kc=(i>>6)&7, ln=i&63;
      src = hs_W + (size_t)(kc*32 + 8*(ln>>4))*128 + ct*16 + (ln&15);
      dst = hsWt + (size_t)i*8; ldw=128;
    } else if (u < 24576){                           // W1t: 5 x (ct8 kc8)
      int v=u-4096, g=v>>12, i=v&4095, ct=i>>9, kc=(i>>6)&7, ln=i&63;
      src = W1 + (size_t)g*32768 + (size_t)(kc*32 + 8*(ln>>4))*128 + ct*16 + (ln&15);
      dst = W1t + (size_t)g*32768 + i*8; ldw=128;
    } else if (u < 34816){                           // W2t: 5 x (ct8 kc4)
      int v=u-24576, g=v>>11, i=v&2047, ct=i>>8, kc=(i>>6)&3, ln=i&63;
      src = W2 + (size_t)g*16384 + (size_t)(kc*32 + 8*(ln>>4))*128 + ct*16 + (ln&15);
      dst = W2t + (size_t)g*16384 + i*8; ldw=128;
    } else if (u < 45056){                           // W3t: 5 x (ct8 kc4)
      int v=u-34816, g=v>>11, i=v&2047, ct=i>>8, kc=(i>>6)&3, ln=i&63;
      src = W3 + (size_t)g*16384 + (size_t)(kc*32 + 8*(ln>>4))*128 + ct*16 + (ln&15);
      dst = W3t + (size_t)g*16384 + i*8; ldw=128;
    } else {                                         // Wit: 5 x (ct24 kc4)
      int v=u-45056, g=v/6144, i=v%6144, ct=i>>8, kc=(i>>6)&3, ln=i&63;
      src = Wi + (size_t)g*49152 + (size_t)(kc*32 + 8*(ln>>4))*384 + ct*16 + (ln&15);
      dst = Wit + (size_t)g*49152 + i*8; ldw=384;
    }
    short8 o;
#pragma unroll
    for (int j=0;j<8;++j) o[j] = f2bf(src[(size_t)j*ldw]);
    *(short8*)dst = o;
  }
  // count: 896 chunks of 256 (chunk fully inside one level)
  for (int c0 = blk; c0 < 896; c0 += NB){
    int* lc = (int*)Xs;
    __syncthreads();
    if (tid < GG) lc[tid] = 0;
    __syncthreads();
    int idx = c0*256 + tid;
    int li = idx >> 15, m = idx & 32767;
    int g = gate[(li+1)*MM + m];
    atomicAdd(&lc[g], 1);
    __syncthreads();
    if (tid < GG && lc[tid] > 0) atomicAdd(&cnt[li*GG + tid], lc[tid]);
  }
  gbar(bar, NB*1);

  // ---------------- Phase B: offsets + pad fill (blocks 0..6) --------
  if (blk < LL-1){
    int* lds_i = (int*)Xs;
    if (tid == 0){
      int l = blk, o = 0;
      for (int g2 = 0; g2 < GG; ++g2){
        off[l*GG+g2] = o;
        int c = cnt[l*GG+g2];
        pend[l*GG+g2] = o + c;
        lds_i[g2] = o + c;
        o += ((c + 31) >> 5) << 5;          // pad bucket to 32
        lds_i[8+g2] = o;
      }
      pad_end[l] = o;
    }
    __syncthreads();
    for (int b2 = 0; b2 < GG; ++b2)
      for (int i = lds_i[b2] + tid; i < lds_i[8+b2]; i += 256)
        sorted[blk*SORT_STRIDE + i] = -1;
  }
  gbar(bar, NB*2);

  // ---------------- Phase C: scatter + hs + level-0 hf zero ----------
  for (int c0 = blk; c0 < 896; c0 += NB){
    int* lc = (int*)Xs; int* base = lc + 8;
    __syncthreads();
    if (tid < GG) lc[tid] = 0;
    __syncthreads();
    int idx = c0*256 + tid;
    int li = idx >> 15, m = idx & 32767;
    int g = gate[(li+1)*MM + m];
    int p = atomicAdd(&lc[g], 1);
    __syncthreads();
    if (tid < GG) base[tid] = atomicAdd(&cur[li*GG + tid], lc[tid]);
    __syncthreads();
    sorted[li*SORT_STRIDE + off[li*GG+g] + base[g] + p] = m;
  }
  // hs items: 4096 x 64 rows
  for (int it = blk; it < 4096; it += NB){
    const int row0 = it*64;
    __syncthreads();                       // protect prior item's Xs reads
    {
      const int r = tid>>2, p = tid&3;
      const float* srow = s + (size_t)(row0+r)*DD;
      const float* trow = t + (size_t)(row0+r)*DD;
      const int rf = r>>4, rl = r&15;
#pragma unroll
      for (int i=0;i<8;++i){
        int u = p + 4*i;
        const float* pp = (u<16) ? (srow + 8*u) : (trow + 8*(u-16));
        short8 v = pack8(*(const f32x4*)pp, *(const f32x4*)(pp+4));
        *(short8*)(Xs + ((rf*8+(u>>2))*64 + (u&3)*16 + rl)*8) = v;
      }
    }
    if (row0 < MM){                        // level-0 hf zero-fill
      short8 zs8 = {0,0,0,0,0,0,0,0};
      const size_t basei = (size_t)row0*DD;
      for (int i=tid; i<2048; i+=256) *(f32x4*)(hf + basei + i*4) = zf;
      for (int i=tid; i<1024; i+=256) *(short8*)(hf_sh + basei + i*8) = zs8;
    }
    __syncthreads();

    f32x4 acc[4][2];
#pragma unroll
    for (int rr=0;rr<4;++rr){ acc[rr][0]=zf; acc[rr][1]=zf; }
    const short* Ab = hsWt + lane*8;
#pragma unroll
    for (int kc=0;kc<8;++kc){
      short8 a0 = *(const short8*)(Ab + (16*w + kc)*512);
      short8 a1 = *(const short8*)(Ab + (16*w + 8 + kc)*512);
#pragma unroll
      for (int rr=0;rr<4;++rr){
        short8 bx = *(const short8*)(Xs + ((rr*8 + kc)*64 + lane)*8);
        acc[rr][0] = MFMA16(a0, bx, acc[rr][0]);
        acc[rr][1] = MFMA16(a1, bx, acc[rr][1]);
      }
    }
    f32x4 bv0 = *(const f32x4*)(hs_b + 32*w + 4*lq);
    f32x4 bv1 = *(const f32x4*)(hs_b + 32*w + 16 + 4*lq);
#pragma unroll
    for (int rr=0;rr<4;++rr){
      int row = row0 + rr*16 + l15;
#pragma unroll
      for (int q=0;q<2;++q){
        f32x4 bv = q ? bv1 : bv0;
        int col = 32*w + 16*q + 4*lq;
        f32x4 o; short4v pk;
#pragma unroll
        for (int j=0;j<4;++j){ o[j] = acc[rr][q][j] + bv[j]; pk[j] = f2bf(o[j]); }
        *(f32x4*)(hs + (size_t)row*DD + col) = o;
        *(short4v*)(hs_sh + (size_t)row*DD + col) = pk;
      }
    }
  }
  gbar(bar, NB*3);

  // ---------------- Phases D..J: levels 1..7 -------------------------
  for (int lvl = 1; lvl < LL; ++lvl){
    const int li = lvl-1;
    const int pe = pad_end[li];
    for (int it = blk; it*32 < pe; it += NB){
      const int pos0 = it*32;
      __syncthreads();                     // protect prior item's LDS
      if (tid==0){
        int g=-1;
        for (int q=0;q<GG;++q)
          if (pos0>=off[li*GG+q] && pos0<pend[li*GG+q]){ g=q; break; }
        ginfo=g;
      }
      if (tid<32) nodebuf[tid] = sorted[li*SORT_STRIDE + pos0 + tid];
      if (tid<64){
        int mg = sorted[li*SORT_STRIDE + pos0 + (tid>>1)];
        srcbuf[tid] = (mg>=0) ? li*MM + fanin[((size_t)li*MM+mg)*FF + (tid&1)] : 0;
      }
      __syncthreads();                                  // B0
      const int g = ginfo;
      if (g >= 0){                                      // block-uniform skip
        // gather X rows into fragment layout
        {
          const int r = tid>>2, p = tid&3;
          const int src = srcbuf[r];
          const short* hsrow = hs_sh + (size_t)src*DD;
          const short* hfrow = hf_sh + (size_t)src*DD;
          const int rf = r>>4, rl = r&15;
#pragma unroll
          for (int i=0;i<8;++i){
            int u = p + 4*i;
            short8 v = *(const short8*)((u<16) ? (hsrow + 8*u) : (hfrow + 8*(u-16)));
            *(short8*)(Xs + ((rf*8+(u>>2))*64 + (u&3)*16 + rl)*8) = v;
          }
        }
        __syncthreads();                                // B1

        // ---- GEMM1: K=256 ----
        f32x4 acc[4][2];
#pragma unroll
        for (int rr=0;rr<4;++rr){ acc[rr][0]=zf; acc[rr][1]=zf; }
        const short* A1 = W1t + (size_t)g*32768 + lane*8;
#pragma unroll
        for (int kc=0;kc<8;++kc){
          short8 a0 = *(const short8*)(A1 + (16*w + kc)*512);
          short8 a1 = *(const short8*)(A1 + (16*w + 8 + kc)*512);
#pragma unroll
          for (int rr=0;rr<4;++rr){
            short8 bx = *(const short8*)(Xs + ((rr*8 + kc)*64 + lane)*8);
            acc[rr][0] = MFMA16(a0, bx, acc[rr][0]);
            acc[rr][1] = MFMA16(a1, bx, acc[rr][1]);
          }
        }
        __syncthreads();                                // B2
        {
          f32x4 bv0 = *(const f32x4*)(b1 + g*DD + 32*w + 4*lq);
          f32x4 bv1 = *(const f32x4*)(b1 + g*DD + 32*w + 16 + 4*lq);
#pragma unroll
          for (int rr=0;rr<4;++rr){
#pragma unroll
            for (int q=0;q<2;++q){
              f32x4 bv = q ? bv1 : bv0;
              short4v pk;
#pragma unroll
              for (int j=0;j<4;++j) pk[j] = f2bf(fmaxf(acc[rr][q][j] + bv[j], 0.f));
              *(short4v*)(Xs + ((rr*4 + w)*64 + (2*q + (lq>>1))*16 + l15)*8 + 4*(lq&1)) = pk;
            }
          }
        }
        __syncthreads();                                // B3

        // ---- GEMM2: K=128 ----
        f32x4 acc2[4][2];
#pragma unroll
        for (int rr=0;rr<4;++rr){ acc2[rr][0]=zf; acc2[rr][1]=zf; }
        const short* A2 = W2t + (size_t)g*16384 + lane*8;
#pragma unroll
        for (int kc=0;kc<4;++kc){
          short8 a0 = *(const short8*)(A2 + (8*w + kc)*512);
          short8 a1 = *(const short8*)(A2 + (8*w + 4 + kc)*512);
#pragma unroll
          for (int rr=0;rr<4;++rr){
            short8 bx = *(const short8*)(Xs + ((rr*4 + kc)*64 + lane)*8);
            acc2[rr][0] = MFMA16(a0, bx, acc2[rr][0]);
            acc2[rr][1] = MFMA16(a1, bx, acc2[rr][1]);
          }
        }
        {
          f32x4 bv0 = *(const f32x4*)(b2 + g*DD + 32*w + 4*lq);
          f32x4 bv1 = *(const f32x4*)(b2 + g*DD + 32*w + 16 + 4*lq);
#pragma unroll
          for (int rr=0;rr<4;++rr){
#pragma unroll
            for (int q=0;q<2;++q){
              f32x4 bv = q ? bv1 : bv0;
              short4v pk;
#pragma unroll
              for (int j=0;j<4;++j) pk[j] = f2bf(fmaxf(acc2[rr][q][j] + bv[j], 0.f));
              *(short4v*)(Xs + 8192 + ((rr*4 + w)*64 + (2*q + (lq>>1))*16 + l15)*8 + 4*(lq&1)) = pk;
            }
          }
        }
        __syncthreads();                                // B4

        // ---- GEMM3: K=128 ----
        f32x4 acc3[4][2];
#pragma unroll
        for (int rr=0;rr<4;++rr){ acc3[rr][0]=zf; acc3[rr][1]=zf; }
        const short* A3 = W3t + (size_t)g*16384 + lane*8;
#pragma unroll
        for (int kc=0;kc<4;++kc){
          short8 a0 = *(const short8*)(A3 + (8*w + kc)*512);
          short8 a1 = *(const short8*)(A3 + (8*w + 4 + kc)*512);
#pragma unroll
          for (int rr=0;rr<4;++rr){
            short8 bx = *(const short8*)(Xs + 8192 + ((rr*4 + kc)*64 + lane)*8);
            acc3[rr][0] = MFMA16(a0, bx, acc3[rr][0]);
            acc3[rr][1] = MFMA16(a1, bx, acc3[rr][1]);
          }
        }
        // pair-sum over F -> msg into Xs[0:4096)
        {
          f32x4 bv0 = *(const f32x4*)(b3 + g*DD + 32*w + 4*lq);
          f32x4 bv1 = *(const f32x4*)(b3 + g*DD + 32*w + 16 + 4*lq);
#pragma unroll
          for (int rr=0;rr<4;++rr){
#pragma unroll
            for (int q=0;q<2;++q){
              f32x4 bv = q ? bv1 : bv0;
              f32x4 mv;
#pragma unroll
              for (int j=0;j<4;++j){
                float v = acc3[rr][q][j];
                mv[j] = v + __shfl_xor(v, 1) + 2.f*bv[j];
              }
              if ((l15 & 1) == 0){
                int n = rr*8 + (l15>>1);               // node 0..31
                short4v pk;
#pragma unroll
                for (int j=0;j<4;++j) pk[j] = f2bf(mv[j]);
                *(short4v*)(Xs + (((n>>4)*4 + w)*64 + (2*q + (lq>>1))*16 + (n&15))*8 + 4*(lq&1)) = pk;
              }
            }
          }
        }
        __syncthreads();                                // B5

        // ---- GRU (2 q-passes) ----
        const short* AW = Wit + (size_t)g*49152 + lane*8;
        const int lo = lvl*MM;
#pragma unroll
        for (int q=0;q<2;++q){
          f32x4 gr[2], gz[2], gn[2];
          gr[0]=zf; gr[1]=zf; gz[0]=zf; gz[1]=zf; gn[0]=zf; gn[1]=zf;
#pragma unroll
          for (int kc=0;kc<4;++kc){
            int cti = ((2*w + q)*4 + kc)*512;
            short8 aR = *(const short8*)(AW + cti);
            short8 aZ = *(const short8*)(AW + 16384 + cti);
            short8 aN = *(const short8*)(AW + 32768 + cti);
#pragma unroll
            for (int rfm=0;rfm<2;++rfm){
              short8 bm = *(const short8*)(Xs + ((rfm*4 + kc)*64 + lane)*8);
              gr[rfm] = MFMA16(aR, bm, gr[rfm]);
              gz[rfm] = MFMA16(aZ, bm, gz[rfm]);
              gn[rfm] = MFMA16(aN, bm, gn[rfm]);
            }
          }
          int col = 32*w + 16*q + 4*lq;
          f32x4 biR = *(const f32x4*)(bi + g*384 + col);
          f32x4 biZ = *(const f32x4*)(bi + g*384 + 128 + col);
          f32x4 biN = *(const f32x4*)(bi + g*384 + 256 + col);
          f32x4 bhR = *(const f32x4*)(bh + g*384 + col);
          f32x4 bhZ = *(const f32x4*)(bh + g*384 + 128 + col);
          f32x4 bhN = *(const f32x4*)(bh + g*384 + 256 + col);
#pragma unroll
          for (int rfm=0;rfm<2;++rfm){
            int m = nodebuf[rfm*16 + l15];
            if (m < 0) continue;
            f32x4 o; short4v pk;
#pragma unroll
            for (int j=0;j<4;++j){
              float xr = gr[rfm][j] + biR[j] + bhR[j];
              float xz = gz[rfm][j] + biZ[j] + bhZ[j];
              float r_ = 1.f/(1.f + __expf(-xr));
              float z_ = 1.f/(1.f + __expf(-xz));
              float xn = gn[rfm][j] + biN[j] + r_*bhN[j];
              float n_ = 2.f/(1.f + __expf(-2.f*xn)) - 1.f;
              o[j] = (1.f - z_)*n_;
              pk[j] = f2bf(o[j]);
            }
            *(f32x4*)(hf + (size_t)(lo + m)*DD + col) = o;
            *(short4v*)(hf_sh + (size_t)(lo + m)*DD + col) = pk;
          }
        }
      } // g >= 0
    } // items
    if (lvl < LL-1) gbar(bar, NB*(3+lvl));
  } // levels
}

extern "C" void kernel_launch(void* const* d_in, const int* in_sizes, int n_in,
                              void* d_out, int out_size, void* d_ws, size_t ws_size,
                              hipStream_t stream)
{
  const float* s    = (const float*)d_in[0];
  const float* t    = (const float*)d_in[1];
  const int*   gate = (const int*)d_in[2];
  const int*   fanin= (const int*)d_in[3];
  const float* hs_W = (const float*)d_in[4];
  const float* hs_b = (const float*)d_in[5];
  const float* W1   = (const float*)d_in[6];
  const float* b1   = (const float*)d_in[7];
  const float* W2   = (const float*)d_in[8];
  const float* b2   = (const float*)d_in[9];
  const float* W3   = (const float*)d_in[10];
  const float* b3   = (const float*)d_in[11];
  const float* Wi   = (const float*)d_in[12];
  // d_in[13] = gru_Wh: unused (hidden state is exactly zero)
  const float* bi   = (const float*)d_in[14];
  const float* bh   = (const float*)d_in[15];

  float* hs = (float*)d_out;
  float* hf = hs + (size_t)NN*DD;

  int* cnt     = (int*)d_ws;       // [7][5]
  int* cur     = cnt + 35;         // [7][5]
  int* off     = cnt + 70;         // [7][5]
  int* pendv   = cnt + 105;        // [7][5]
  int* pad_end = cnt + 140;        // [7]
  int* bar     = cnt + 160;        // barrier counter (own line)
  int* sorted  = cnt + 256;        // 7*SORT_STRIDE ints, < 1 MB

  short* wbase = (short*)((char*)d_ws + (1<<20));
  short* hsWt = wbase;             // 4096*8
  short* W1t  = wbase + 32768;     // 5*32768
  short* W2t  = wbase + 196608;    // 5*16384
  short* W3t  = wbase + 278528;    // 5*16384
  short* Wit  = wbase + 360448;    // 5*49152

  short* hs_sh = (short*)((char*)d_ws + (size_t)(8<<20));   // [N][128] bf16
  short* hf_sh = hs_sh + (size_t)NN*DD;                      // [N][128] bf16

  // co-residency-safe grid size (host-side query; graph-capture legal)
  int nper = 0;
  hipOccupancyMaxActiveBlocksPerMultiprocessor(&nper, mega_kernel, 256, 0);
  if (nper < 1) nper = 1;
  int NBLK = nper * 256;           // 256 CUs on MI355X
  if (NBLK > 1024) NBLK = 1024;

  hipMemsetAsync(d_ws, 0, 1024, stream);   // cnt/cur/off/pend/pad_end/bar = 0
  mega_kernel<<<NBLK, 256, 0, stream>>>(
      s, t, gate, fanin, hs_W, hs_b, W1, b1, W2, b2, W3, b3, Wi, bi, bh,
      hs, hf, hsWt, W1t, W2t, W3t, Wit, hs_sh, hf_sh,
      cnt, cur, off, pendv, pad_end, sorted, bar);
}

// Round 10
// 702.463 us; speedup vs baseline: 2.1382x; 1.2893x over previous
//
#include <hip/hip_runtime.h>
#include <hip/hip_bf16.h>

#define DD 128
#define LL 8
#define MM 32768
#define NN (LL*MM)
#define GG 5
#define FF 2
#define SORT_STRIDE 33408   // 32768 + headroom (>= 5*31 pad)

typedef __attribute__((ext_vector_type(8))) short short8;
typedef __attribute__((ext_vector_type(4))) short short4v;
typedef __attribute__((ext_vector_type(4))) float f32x4;

#define MFMA16(a,b,c) __builtin_amdgcn_mfma_f32_16x16x32_bf16((a),(b),(c),0,0,0)

__device__ __forceinline__ short f2bf(float x){
  __hip_bfloat16 h = __float2bfloat16(x);
  return *reinterpret_cast<short*>(&h);
}

__device__ __forceinline__ short8 pack8(f32x4 a, f32x4 b){
  short8 r;
  r[0]=f2bf(a[0]); r[1]=f2bf(a[1]); r[2]=f2bf(a[2]); r[3]=f2bf(a[3]);
  r[4]=f2bf(b[0]); r[5]=f2bf(b[1]); r[6]=f2bf(b[2]); r[7]=f2bf(b[3]);
  return r;
}

// ---------------- one-time weight convert to fragment-contiguous bf16 ------
// Layout per tensor: [g][ct][kc][lane][8]  (ct = 16-col tile, kc = 32-k tile)
// value[j] = W[k = kc*32 + 8*(lane>>4) + j][col = ct*16 + (lane&15)]
__global__ void prep_kernel(const float* __restrict__ hs_W, const float* __restrict__ W1,
                            const float* __restrict__ W2, const float* __restrict__ W3,
                            const float* __restrict__ Wi,
                            short* __restrict__ hsWt, short* __restrict__ W1t,
                            short* __restrict__ W2t, short* __restrict__ W3t,
                            short* __restrict__ Wit, int* __restrict__ cntcur)
{
  if (blockIdx.x == 0 && threadIdx.x < 70) cntcur[threadIdx.x] = 0;  // cnt[35]+cur[35]
  int u = blockIdx.x*256 + threadIdx.x;   // 75776 units of 8 k-elems
  const float* src; short* dst; int ldw;
  if (u < 4096){                                   // hsWt: ct8 kc8
    int i=u, ct=i>>9, kc=(i>>6)&7, ln=i&63;
    src = hs_W + (size_t)(kc*32 + 8*(ln>>4))*128 + ct*16 + (ln&15);
    dst = hsWt + (size_t)i*8; ldw=128;
  } else if (u < 24576){                           // W1t: 5 x (ct8 kc8)
    int v=u-4096, g=v>>12, i=v&4095, ct=i>>9, kc=(i>>6)&7, ln=i&63;
    src = W1 + (size_t)g*32768 + (size_t)(kc*32 + 8*(ln>>4))*128 + ct*16 + (ln&15);
    dst = W1t + (size_t)g*32768 + i*8; ldw=128;
  } else if (u < 34816){                           // W2t: 5 x (ct8 kc4)
    int v=u-24576, g=v>>11, i=v&2047, ct=i>>8, kc=(i>>6)&3, ln=i&63;
    src = W2 + (size_t)g*16384 + (size_t)(kc*32 + 8*(ln>>4))*128 + ct*16 + (ln&15);
    dst = W2t + (size_t)g*16384 + i*8; ldw=128;
  } else if (u < 45056){                           // W3t: 5 x (ct8 kc4)
    int v=u-34816, g=v>>11, i=v&2047, ct=i>>8, kc=(i>>6)&3, ln=i&63;
    src = W3 + (size_t)g*16384 + (size_t)(kc*32 + 8*(ln>>4))*128 + ct*16 + (ln&15);
    dst = W3t + (size_t)g*16384 + i*8; ldw=128;
  } else {                                         // Wit: 5 x (ct24 kc4)
    int v=u-45056, g=v/6144, i=v%6144, ct=i>>8, kc=(i>>6)&3, ln=i&63;
    src = Wi + (size_t)g*49152 + (size_t)(kc*32 + 8*(ln>>4))*384 + ct*16 + (ln&15);
    dst = Wit + (size_t)g*49152 + i*8; ldw=384;
  }
  short8 o;
#pragma unroll
  for (int j=0;j<8;++j) o[j] = f2bf(src[(size_t)j*ldw]);
  *(short8*)dst = o;
}

// ---------------- bucket sort by gate, per level ----------------
__global__ void count_kernel(const int* __restrict__ gate, int* __restrict__ cnt){
  __shared__ int lc[GG];
  const int li = blockIdx.x >> 7;
  const int m  = ((blockIdx.x & 127) << 8) + threadIdx.x;
  if (threadIdx.x < GG) lc[threadIdx.x] = 0;
  __syncthreads();
  int g = gate[(li+1)*MM + m];
  atomicAdd(&lc[g], 1);
  __syncthreads();
  if (threadIdx.x < GG && lc[threadIdx.x] > 0)
    atomicAdd(&cnt[li*GG + threadIdx.x], lc[threadIdx.x]);
}

// offsets (pad 32) + fill pad slots with -1
__global__ void offs_kernel(const int* __restrict__ cnt, int* __restrict__ off,
                            int* __restrict__ pend, int* __restrict__ pad_end,
                            int* __restrict__ sorted){
  __shared__ int se[35], sp[35];
  const int tid = threadIdx.x;
  if (tid < LL-1){
    int l = tid, o = 0;
    for (int g = 0; g < GG; ++g){
      off[l*GG+g] = o;
      int c = cnt[l*GG+g];
      pend[l*GG+g] = o + c;
      se[l*GG+g] = o + c;
      o += ((c + 31) >> 5) << 5;          // pad each bucket to 32
      sp[l*GG+g] = o;
    }
    pad_end[l] = o;
  }
  __syncthreads();
  for (int b = 0; b < 35; ++b){
    int l = b / GG;
    for (int i = se[b] + tid; i < sp[b]; i += 256)
      sorted[l*SORT_STRIDE + i] = -1;
  }
}

__global__ void scatter_kernel(const int* __restrict__ gate, const int* __restrict__ off,
                               int* __restrict__ cur, int* __restrict__ sorted){
  __shared__ int lc[GG];
  __shared__ int base[GG];
  const int li = blockIdx.x >> 7;
  const int m  = ((blockIdx.x & 127) << 8) + threadIdx.x;
  if (threadIdx.x < GG) lc[threadIdx.x] = 0;
  __syncthreads();
  int g = gate[(li+1)*MM + m];
  int p = atomicAdd(&lc[g], 1);
  __syncthreads();
  if (threadIdx.x < GG)
    base[threadIdx.x] = atomicAdd(&cur[li*GG + threadIdx.x], lc[threadIdx.x]);
  __syncthreads();
  sorted[li*SORT_STRIDE + off[li*GG+g] + base[g] + p] = m;
}

// ---------------- hs = [s|t] @ hs_W + hs_b  (+ level-0 hf zero-fill) -------
// Row-split waves: wave w owns rows 16w..16w+15, ALL 128 cols. Zero LDS,
// zero barriers. B-fragments loaded directly from s/t (per-lane row = l15).
__global__ __launch_bounds__(256,4) void hs_kernel(
    const float* __restrict__ s, const float* __restrict__ t,
    const short* __restrict__ Wt, const float* __restrict__ b,
    float* __restrict__ hs, short* __restrict__ hs_sh,
    float* __restrict__ hf, short* __restrict__ hf_sh)
{
  const int tid=threadIdx.x, lane=tid&63, w=tid>>6;
  const int l15=lane&15, lq=lane>>4;
  const int row0 = blockIdx.x*64;
  const int row = row0 + 16*w + l15;

  // level-0 hf zero-fill (replaces memset nodes)
  if (row0 < MM){
    f32x4 zf4 = {0.f,0.f,0.f,0.f};
    short8 zs8 = {0,0,0,0,0,0,0,0};
    const size_t basei = (size_t)row0*DD;
    for (int i=tid; i<2048; i+=256) *(f32x4*)(hf + basei + i*4) = zf4;
    for (int i=tid; i<1024; i+=256) *(short8*)(hf_sh + basei + i*8) = zs8;
  }

  f32x4 zf = {0.f,0.f,0.f,0.f};
  f32x4 acc[8];
#pragma unroll
  for (int ct=0;ct<8;++ct) acc[ct] = zf;

  const float* srow = s + (size_t)row*DD + 8*lq;
  const float* trow = t + (size_t)row*DD + 8*lq;
  const short* Ab = Wt + lane*8;
#pragma unroll
  for (int kc=0;kc<8;++kc){
    const float* p = (kc<4) ? (srow + kc*32) : (trow + (kc-4)*32);
    short8 bx = pack8(*(const f32x4*)p, *(const f32x4*)(p+4));
#pragma unroll
    for (int ct=0;ct<8;++ct){
      short8 a0 = *(const short8*)(Ab + (ct*8 + kc)*512);
      acc[ct] = MFMA16(a0, bx, acc[ct]);
    }
  }
#pragma unroll
  for (int ct=0;ct<8;++ct){
    f32x4 bv = *(const f32x4*)(b + ct*16 + 4*lq);
    f32x4 o; short4v pk;
#pragma unroll
    for (int j=0;j<4;++j){ o[j] = acc[ct][j] + bv[j]; pk[j] = f2bf(o[j]); }
    *(f32x4*)(hs + (size_t)row*DD + ct*16 + 4*lq) = o;
    *(short4v*)(hs_sh + (size_t)row*DD + ct*16 + 4*lq) = pk;
  }
}

// ---------------- fused per-level kernel: row-split waves ------------------
// 32 nodes/block, 4 waves; wave w owns X rows 16w..16w+15 (nodes 8w..8w+7),
// all 128 cols. MLP chain is wave-private (LDS bounce, no __syncthreads);
// ONE block barrier before the col-split GRU.
__global__ __launch_bounds__(256,4) void level_kernel(
    int lvl, float* __restrict__ hfg,
    const short* __restrict__ hs_sh, short* __restrict__ hf_sh,
    const int* __restrict__ fanin,
    const short* __restrict__ W1t, const short* __restrict__ W2t,
    const short* __restrict__ W3t, const short* __restrict__ Wit,
    const float* __restrict__ b1, const float* __restrict__ b2,
    const float* __restrict__ b3, const float* __restrict__ bi,
    const float* __restrict__ bh,
    const int* __restrict__ off, const int* __restrict__ pend,
    const int* __restrict__ pad_end, const int* __restrict__ sorted)
{
  __shared__ __align__(16) short bounce[4][16*136];   // wave-private H1/H2
  __shared__ __align__(16) short msgb[32*136];        // block-shared msg

  const int tid=threadIdx.x, lane=tid&63, w=tid>>6;  // w = 0..3
  const int l15=lane&15, lq=lane>>4;
  const int li = lvl-1;
  const int pos0 = blockIdx.x*32;

  if (pos0 >= pad_end[li]) return;        // uniform: block beyond level's work

  int g = -1;
#pragma unroll
  for (int q=0;q<GG;++q)
    if (pos0 >= off[li*GG+q] && pos0 < pend[li*GG+q]) g = q;
  if (g < 0) return;                      // uniform (shouldn't happen)

  // per-lane source row: X row r = 16w + l15  -> (node r>>1, fanin r&1)
  const int r = 16*w + l15;
  const int mg = sorted[li*SORT_STRIDE + pos0 + (r>>1)];
  const int src = (mg>=0) ? li*MM + fanin[((size_t)li*MM+mg)*FF + (r&1)] : 0;
  const short* hsrow = hs_sh + (size_t)src*DD + 8*lq;
  const short* hfrow = hf_sh + (size_t)src*DD + 8*lq;

  f32x4 zf = {0.f,0.f,0.f,0.f};
  short* hb = bounce[w];

  // ---- GEMM1: K=256, B direct from global (gathered rows) ----
  f32x4 acc[8];
#pragma unroll
  for (int ct=0;ct<8;++ct) acc[ct] = zf;
  const short* A1 = W1t + (size_t)g*32768 + lane*8;
#pragma unroll
  for (int kc=0;kc<8;++kc){
    short8 bx = (kc<4) ? *(const short8*)(hsrow + kc*32)
                       : *(const short8*)(hfrow + (kc-4)*32);
#pragma unroll
    for (int ct=0;ct<8;++ct)
      acc[ct] = MFMA16(*(const short8*)(A1 + (ct*8 + kc)*512), bx, acc[ct]);
  }
  // H1 -> wave-private bounce (no barrier: same-wave LDS RAW via lgkmcnt)
#pragma unroll
  for (int ct=0;ct<8;++ct){
    f32x4 bv = *(const f32x4*)(b1 + g*DD + ct*16 + 4*lq);
    short4v pk;
#pragma unroll
    for (int j=0;j<4;++j) pk[j] = f2bf(fmaxf(acc[ct][j] + bv[j], 0.f));
    *(short4v*)(hb + l15*136 + ct*16 + 4*lq) = pk;
  }

  // ---- GEMM2: K=128, B from bounce ----
  f32x4 acc2[8];
#pragma unroll
  for (int ct=0;ct<8;++ct) acc2[ct] = zf;
  const short* A2 = W2t + (size_t)g*16384 + lane*8;
#pragma unroll
  for (int kc=0;kc<4;++kc){
    short8 bx = *(const short8*)(hb + l15*136 + kc*32 + 8*lq);
#pragma unroll
    for (int ct=0;ct<8;++ct)
      acc2[ct] = MFMA16(*(const short8*)(A2 + (ct*4 + kc)*512), bx, acc2[ct]);
  }
  // H2 overwrites bounce in place (wave-ordered DS ops make this safe)
#pragma unroll
  for (int ct=0;ct<8;++ct){
    f32x4 bv = *(const f32x4*)(b2 + g*DD + ct*16 + 4*lq);
    short4v pk;
#pragma unroll
    for (int j=0;j<4;++j) pk[j] = f2bf(fmaxf(acc2[ct][j] + bv[j], 0.f));
    *(short4v*)(hb + l15*136 + ct*16 + 4*lq) = pk;
  }

  // ---- GEMM3: K=128, B from bounce ----
  f32x4 acc3[8];
#pragma unroll
  for (int ct=0;ct<8;++ct) acc3[ct] = zf;
  const short* A3 = W3t + (size_t)g*16384 + lane*8;
#pragma unroll
  for (int kc=0;kc<4;++kc){
    short8 bx = *(const short8*)(hb + l15*136 + kc*32 + 8*lq);
#pragma unroll
    for (int ct=0;ct<8;++ct)
      acc3[ct] = MFMA16(*(const short8*)(A3 + (ct*4 + kc)*512), bx, acc3[ct]);
  }
  // pair-sum over F (adjacent l15 lanes = same node's two fanins) -> msgb
#pragma unroll
  for (int ct=0;ct<8;++ct){
    f32x4 bv = *(const f32x4*)(b3 + g*DD + ct*16 + 4*lq);
    f32x4 mv;
#pragma unroll
    for (int j=0;j<4;++j){
      float v = acc3[ct][j];
      mv[j] = v + __shfl_xor(v, 1) + 2.f*bv[j];
    }
    if ((l15 & 1) == 0){
      int n = 8*w + (l15>>1);             // node 0..31
      short4v pk;
#pragma unroll
      for (int j=0;j<4;++j) pk[j] = f2bf(mv[j]);
      *(short4v*)(msgb + n*136 + ct*16 + 4*lq) = pk;
    }
  }
  __syncthreads();                        // ONLY block barrier: msg ready

  // ---- GRU: col-split (wave w -> cols 32w..32w+31 of r/z/n); h==0 ----
  const short* AW = Wit + (size_t)g*49152 + lane*8;
  const int lo = lvl*MM;
#pragma unroll
  for (int q=0;q<2;++q){
    f32x4 gr[2], gz[2], gn[2];
    gr[0]=zf; gr[1]=zf; gz[0]=zf; gz[1]=zf; gn[0]=zf; gn[1]=zf;
#pragma unroll
    for (int kc=0;kc<4;++kc){
      int cti = ((2*w + q)*4 + kc)*512;
      short8 aR = *(const short8*)(AW + cti);
      short8 aZ = *(const short8*)(AW + 16384 + cti);
      short8 aN = *(const short8*)(AW + 32768 + cti);
#pragma unroll
      for (int rfm=0;rfm<2;++rfm){
        short8 bm = *(const short8*)(msgb + (rfm*16 + l15)*136 + kc*32 + 8*lq);
        gr[rfm] = MFMA16(aR, bm, gr[rfm]);
        gz[rfm] = MFMA16(aZ, bm, gz[rfm]);
        gn[rfm] = MFMA16(aN, bm, gn[rfm]);
      }
    }
    int col = 32*w + 16*q + 4*lq;
    f32x4 biR = *(const f32x4*)(bi + g*384 + col);
    f32x4 biZ = *(const f32x4*)(bi + g*384 + 128 + col);
    f32x4 biN = *(const f32x4*)(bi + g*384 + 256 + col);
    f32x4 bhR = *(const f32x4*)(bh + g*384 + col);
    f32x4 bhZ = *(const f32x4*)(bh + g*384 + 128 + col);
    f32x4 bhN = *(const f32x4*)(bh + g*384 + 256 + col);
#pragma unroll
    for (int rfm=0;rfm<2;++rfm){
      int m = sorted[li*SORT_STRIDE + pos0 + rfm*16 + l15];
      if (m < 0) continue;
      f32x4 o; short4v pk;
#pragma unroll
      for (int j=0;j<4;++j){
        float xr = gr[rfm][j] + biR[j] + bhR[j];
        float xz = gz[rfm][j] + biZ[j] + bhZ[j];
        float r_ = 1.f/(1.f + __expf(-xr));
        float z_ = 1.f/(1.f + __expf(-xz));
        float xn = gn[rfm][j] + biN[j] + r_*bhN[j];
        float n_ = 2.f/(1.f + __expf(-2.f*xn)) - 1.f;
        o[j] = (1.f - z_)*n_;
        pk[j] = f2bf(o[j]);
      }
      *(f32x4*)(hfg + (size_t)(lo + m)*DD + col) = o;
      *(short4v*)(hf_sh + (size_t)(lo + m)*DD + col) = pk;
    }
  }
}

extern "C" void kernel_launch(void* const* d_in, const int* in_sizes, int n_in,
                              void* d_out, int out_size, void* d_ws, size_t ws_size,
                              hipStream_t stream)
{
  const float* s    = (const float*)d_in[0];
  const float* t    = (const float*)d_in[1];
  const int*   gate = (const int*)d_in[2];
  const int*   fanin= (const int*)d_in[3];
  const float* hs_W = (const float*)d_in[4];
  const float* hs_b = (const float*)d_in[5];
  const float* W1   = (const float*)d_in[6];
  const float* b1   = (const float*)d_in[7];
  const float* W2   = (const float*)d_in[8];
  const float* b2   = (const float*)d_in[9];
  const float* W3   = (const float*)d_in[10];
  const float* b3   = (const float*)d_in[11];
  const float* Wi   = (const float*)d_in[12];
  // d_in[13] = gru_Wh: unused (hidden state is exactly zero)
  const float* bi   = (const float*)d_in[14];
  const float* bh   = (const float*)d_in[15];

  float* hs = (float*)d_out;
  float* hf = hs + (size_t)NN*DD;

  int* cnt     = (int*)d_ws;       // [7][5]
  int* cur     = cnt + 35;         // [7][5]
  int* off     = cnt + 70;         // [7][5]
  int* pendv   = cnt + 105;        // [7][5]
  int* pad_end = cnt + 140;        // [7]
  int* sorted  = cnt + 256;        // 7*SORT_STRIDE ints, < 1 MB

  short* wbase = (short*)((char*)d_ws + (1<<20));
  short* hsWt = wbase;             // 4096*8
  short* W1t  = wbase + 32768;     // 5*32768
  short* W2t  = wbase + 196608;    // 5*16384
  short* W3t  = wbase + 278528;    // 5*16384
  short* Wit  = wbase + 360448;    // 5*49152

  short* hs_sh = (short*)((char*)d_ws + (size_t)(8<<20));   // [N][128] bf16
  short* hf_sh = hs_sh + (size_t)NN*DD;                      // [N][128] bf16

  prep_kernel<<<296, 256, 0, stream>>>(hs_W, W1, W2, W3, Wi,
                                       hsWt, W1t, W2t, W3t, Wit, cnt);
  count_kernel<<<896, 256, 0, stream>>>(gate, cnt);
  offs_kernel<<<1, 256, 0, stream>>>(cnt, off, pendv, pad_end, sorted);
  scatter_kernel<<<896, 256, 0, stream>>>(gate, off, cur, sorted);
  hs_kernel<<<NN/64, 256, 0, stream>>>(s, t, hsWt, hs_b, hs, hs_sh, hf, hf_sh);
  for (int lvl = 1; lvl < LL; ++lvl){
    level_kernel<<<SORT_STRIDE/32, 256, 0, stream>>>(lvl, hf,
        hs_sh, hf_sh, fanin, W1t, W2t, W3t, Wit,
        b1, b2, b3, bi, bh, off, pendv, pad_end, sorted);
  }
}

// Round 11
// 403.186 us; speedup vs baseline: 3.7254x; 1.7423x over previous
//
#include <hip/hip_runtime.h>
#include <hip/hip_bf16.h>

#define DD 128
#define LL 8
#define MM 32768
#define NN (LL*MM)
#define GG 5
#define FF 2
#define SORT_STRIDE 33408   // 32768 + headroom (>= 5*31 pad)

typedef __attribute__((ext_vector_type(8))) short short8;
typedef __attribute__((ext_vector_type(4))) short short4v;
typedef __attribute__((ext_vector_type(4))) float f32x4;

#define MFMA16(a,b,c) __builtin_amdgcn_mfma_f32_16x16x32_bf16((a),(b),(c),0,0,0)

__device__ __forceinline__ short f2bf(float x){
  __hip_bfloat16 h = __float2bfloat16(x);
  return *reinterpret_cast<short*>(&h);
}

__device__ __forceinline__ short8 pack8(f32x4 a, f32x4 b){
  short8 r;
  r[0]=f2bf(a[0]); r[1]=f2bf(a[1]); r[2]=f2bf(a[2]); r[3]=f2bf(a[3]);
  r[4]=f2bf(b[0]); r[5]=f2bf(b[1]); r[6]=f2bf(b[2]); r[7]=f2bf(b[3]);
  return r;
}

// ---------------- one-time weight convert to fragment-contiguous bf16 ------
// Layout per tensor: [g][ct][kc][lane][8]  (ct = 16-col tile, kc = 32-k tile)
// value[j] = W[k = kc*32 + 8*(lane>>4) + j][col = ct*16 + (lane&15)]
__global__ void prep_kernel(const float* __restrict__ hs_W, const float* __restrict__ W1,
                            const float* __restrict__ W2, const float* __restrict__ W3,
                            const float* __restrict__ Wi,
                            short* __restrict__ hsWt, short* __restrict__ W1t,
                            short* __restrict__ W2t, short* __restrict__ W3t,
                            short* __restrict__ Wit, int* __restrict__ cntcur)
{
  if (blockIdx.x == 0 && threadIdx.x < 70) cntcur[threadIdx.x] = 0;  // cnt[35]+cur[35]
  int u = blockIdx.x*256 + threadIdx.x;   // 75776 units of 8 k-elems
  const float* src; short* dst; int ldw;
  if (u < 4096){                                   // hsWt: ct8 kc8
    int i=u, ct=i>>9, kc=(i>>6)&7, ln=i&63;
    src = hs_W + (size_t)(kc*32 + 8*(ln>>4))*128 + ct*16 + (ln&15);
    dst = hsWt + (size_t)i*8; ldw=128;
  } else if (u < 24576){                           // W1t: 5 x (ct8 kc8)
    int v=u-4096, g=v>>12, i=v&4095, ct=i>>9, kc=(i>>6)&7, ln=i&63;
    src = W1 + (size_t)g*32768 + (size_t)(kc*32 + 8*(ln>>4))*128 + ct*16 + (ln&15);
    dst = W1t + (size_t)g*32768 + i*8; ldw=128;
  } else if (u < 34816){                           // W2t: 5 x (ct8 kc4)
    int v=u-24576, g=v>>11, i=v&2047, ct=i>>8, kc=(i>>6)&3, ln=i&63;
    src = W2 + (size_t)g*16384 + (size_t)(kc*32 + 8*(ln>>4))*128 + ct*16 + (ln&15);
    dst = W2t + (size_t)g*16384 + i*8; ldw=128;
  } else if (u < 45056){                           // W3t: 5 x (ct8 kc4)
    int v=u-34816, g=v>>11, i=v&2047, ct=i>>8, kc=(i>>6)&3, ln=i&63;
    src = W3 + (size_t)g*16384 + (size_t)(kc*32 + 8*(ln>>4))*128 + ct*16 + (ln&15);
    dst = W3t + (size_t)g*16384 + i*8; ldw=128;
  } else {                                         // Wit: 5 x (ct24 kc4)
    int v=u-45056, g=v/6144, i=v%6144, ct=i>>8, kc=(i>>6)&3, ln=i&63;
    src = Wi + (size_t)g*49152 + (size_t)(kc*32 + 8*(ln>>4))*384 + ct*16 + (ln&15);
    dst = Wit + (size_t)g*49152 + i*8; ldw=384;
  }
  short8 o;
#pragma unroll
  for (int j=0;j<8;++j) o[j] = f2bf(src[(size_t)j*ldw]);
  *(short8*)dst = o;
}

// ---------------- bucket sort by gate, per level ----------------
__global__ void count_kernel(const int* __restrict__ gate, int* __restrict__ cnt){
  __shared__ int lc[GG];
  const int li = blockIdx.x >> 7;
  const int m  = ((blockIdx.x & 127) << 8) + threadIdx.x;
  if (threadIdx.x < GG) lc[threadIdx.x] = 0;
  __syncthreads();
  int g = gate[(li+1)*MM + m];
  atomicAdd(&lc[g], 1);
  __syncthreads();
  if (threadIdx.x < GG && lc[threadIdx.x] > 0)
    atomicAdd(&cnt[li*GG + threadIdx.x], lc[threadIdx.x]);
}

// offsets (pad 32) + fill pad slots with -1
__global__ void offs_kernel(const int* __restrict__ cnt, int* __restrict__ off,
                            int* __restrict__ pend, int* __restrict__ sorted){
  __shared__ int se[35], sp[35];
  const int tid = threadIdx.x;
  if (tid < LL-1){
    int l = tid, o = 0;
    for (int g = 0; g < GG; ++g){
      off[l*GG+g] = o;
      int c = cnt[l*GG+g];
      pend[l*GG+g] = o + c;
      se[l*GG+g] = o + c;
      o += ((c + 31) >> 5) << 5;          // pad each bucket to 32
      sp[l*GG+g] = o;
    }
  }
  __syncthreads();
  for (int b = 0; b < 35; ++b){
    int l = b / GG;
    for (int i = se[b] + tid; i < sp[b]; i += 256)
      sorted[l*SORT_STRIDE + i] = -1;
  }
}

__global__ void scatter_kernel(const int* __restrict__ gate, const int* __restrict__ off,
                               int* __restrict__ cur, int* __restrict__ sorted){
  __shared__ int lc[GG];
  __shared__ int base[GG];
  const int li = blockIdx.x >> 7;
  const int m  = ((blockIdx.x & 127) << 8) + threadIdx.x;
  if (threadIdx.x < GG) lc[threadIdx.x] = 0;
  __syncthreads();
  int g = gate[(li+1)*MM + m];
  int p = atomicAdd(&lc[g], 1);
  __syncthreads();
  if (threadIdx.x < GG)
    base[threadIdx.x] = atomicAdd(&cur[li*GG + threadIdx.x], lc[threadIdx.x]);
  __syncthreads();
  sorted[li*SORT_STRIDE + off[li*GG+g] + base[g] + p] = m;
}

// ---------------- hs = [s|t] @ hs_W + hs_b  (+ level-0 hf zero-fill) -------
// Col-split (R7 structure) + EXPLICIT register prefetch: stage loads batched
// into va[16] before pack; all 16 A-fragments preloaded before MFMA loop.
__global__ __launch_bounds__(256,3) void hs_kernel(
    const float* __restrict__ s, const float* __restrict__ t,
    const short* __restrict__ Wt, const float* __restrict__ b,
    float* __restrict__ hs, short* __restrict__ hs_sh,
    float* __restrict__ hf, short* __restrict__ hf_sh)
{
  __shared__ __align__(16) short Xs[16384];
  const int tid=threadIdx.x, lane=tid&63, w=tid>>6;   // w = 0..3
  const int l15=lane&15, lq=lane>>4;
  const int row0 = blockIdx.x*64;

  // stage X rows into fragment layout — batched loads first (16 in flight)
  {
    const int r = tid>>2, p = tid&3;
    const float* srow = s + (size_t)(row0+r)*DD;
    const float* trow = t + (size_t)(row0+r)*DD;
    const int rf = r>>4, rl = r&15;
    f32x4 va[16];
#pragma unroll
    for (int i=0;i<8;++i){
      int u = p + 4*i;
      const float* pp = (u<16) ? (srow + 8*u) : (trow + 8*(u-16));
      va[2*i]   = *(const f32x4*)pp;
      va[2*i+1] = *(const f32x4*)(pp+4);
    }
#pragma unroll
    for (int i=0;i<8;++i){
      int u = p + 4*i;
      short8 v = pack8(va[2*i], va[2*i+1]);
      *(short8*)(Xs + ((rf*8+(u>>2))*64 + (u&3)*16 + rl)*8) = v;
    }
  }

  // level-0 hf zero-fill (replaces memset nodes)
  if (row0 < MM){
    f32x4 zf4 = {0.f,0.f,0.f,0.f};
    short8 zs8 = {0,0,0,0,0,0,0,0};
    const size_t basei = (size_t)row0*DD;
    for (int i=tid; i<2048; i+=256) *(f32x4*)(hf + basei + i*4) = zf4;
    for (int i=tid; i<1024; i+=256) *(short8*)(hf_sh + basei + i*8) = zs8;
  }
  __syncthreads();

  f32x4 zf = {0.f,0.f,0.f,0.f};
  // preload wave's 16 A-fragments (contiguous 16KB at 16w*512 shorts)
  const short* Aw = Wt + (16*w)*512 + lane*8;
  short8 af[16];
#pragma unroll
  for (int i=0;i<16;++i) af[i] = *(const short8*)(Aw + i*512);

  f32x4 acc[4][2];
#pragma unroll
  for (int rr=0;rr<4;++rr){ acc[rr][0]=zf; acc[rr][1]=zf; }
#pragma unroll
  for (int kc=0;kc<8;++kc){
    short8 bx[4];
#pragma unroll
    for (int rr=0;rr<4;++rr)
      bx[rr] = *(const short8*)(Xs + ((rr*8 + kc)*64 + lane)*8);
#pragma unroll
    for (int rr=0;rr<4;++rr){
      acc[rr][0] = MFMA16(af[kc],   bx[rr], acc[rr][0]);   // ct = 2w
      acc[rr][1] = MFMA16(af[8+kc], bx[rr], acc[rr][1]);   // ct = 2w+1
    }
  }

  f32x4 bv0 = *(const f32x4*)(b + 32*w + 4*lq);
  f32x4 bv1 = *(const f32x4*)(b + 32*w + 16 + 4*lq);
#pragma unroll
  for (int rr=0;rr<4;++rr){
    int row = row0 + rr*16 + l15;
#pragma unroll
    for (int q=0;q<2;++q){
      f32x4 bv = q ? bv1 : bv0;
      int col = 32*w + 16*q + 4*lq;
      f32x4 o; short4v pk;
#pragma unroll
      for (int j=0;j<4;++j){ o[j] = acc[rr][q][j] + bv[j]; pk[j] = f2bf(o[j]); }
      *(f32x4*)(hs + (size_t)row*DD + col) = o;
      *(short4v*)(hs_sh + (size_t)row*DD + col) = pk;
    }
  }
}

// ---------------- fused per-level kernel: 32 nodes/block, col-split --------
// R7 structure; every GEMM phase preloads its A-fragments into registers
// (batched vmcnt) instead of serial load->MFMA (the ~30us/level disease).
__global__ __launch_bounds__(256,3) void level_kernel(
    int lvl, float* __restrict__ hfg,
    const short* __restrict__ hs_sh, short* __restrict__ hf_sh,
    const int* __restrict__ fanin,
    const short* __restrict__ W1t, const short* __restrict__ W2t,
    const short* __restrict__ W3t, const short* __restrict__ Wit,
    const float* __restrict__ b1, const float* __restrict__ b2,
    const float* __restrict__ b3, const float* __restrict__ bi,
    const float* __restrict__ bh,
    const int* __restrict__ off, const int* __restrict__ pend,
    const int* __restrict__ sorted)
{
  __shared__ __align__(16) short Xs[16384];
  __shared__ int nodebuf[32];
  __shared__ int srcbuf[64];
  __shared__ int ginfo;

  const int tid=threadIdx.x, lane=tid&63, w=tid>>6;  // w = 0..3
  const int l15=lane&15, lq=lane>>4;
  const int li = lvl-1;
  const int pos0 = blockIdx.x*32;

  if (tid==0){
    int g=-1;
    for (int q=0;q<GG;++q)
      if (pos0>=off[li*GG+q] && pos0<pend[li*GG+q]){ g=q; break; }
    ginfo=g;
  }
  if (tid<32) nodebuf[tid] = sorted[li*SORT_STRIDE + pos0 + tid];
  if (tid<64){
    int mg = sorted[li*SORT_STRIDE + pos0 + (tid>>1)];
    srcbuf[tid] = (mg>=0) ? li*MM + fanin[((size_t)li*MM+mg)*FF + (tid&1)] : 0;
  }
  __syncthreads();                                  // B0
  const int g = ginfo;
  if (g<0) return;                                  // block-uniform

  // gather X rows into fragment layout (batched: 8 loads in flight)
  {
    const int r = tid>>2, p = tid&3;
    const int src = srcbuf[r];
    const short* hsrow = hs_sh + (size_t)src*DD;
    const short* hfrow = hf_sh + (size_t)src*DD;
    const int rf = r>>4, rl = r&15;
    short8 va[8];
#pragma unroll
    for (int i=0;i<8;++i){
      int u = p + 4*i;
      va[i] = *(const short8*)((u<16) ? (hsrow + 8*u) : (hfrow + 8*(u-16)));
    }
#pragma unroll
    for (int i=0;i<8;++i){
      int u = p + 4*i;
      *(short8*)(Xs + ((rf*8+(u>>2))*64 + (u&3)*16 + rl)*8) = va[i];
    }
  }
  __syncthreads();                                  // B1

  f32x4 zf = {0.f,0.f,0.f,0.f};

  // ---- GEMM1: K=256, A preloaded (16 frags, contiguous 16KB) ----
  f32x4 acc[4][2];
#pragma unroll
  for (int rr=0;rr<4;++rr){ acc[rr][0]=zf; acc[rr][1]=zf; }
  {
    const short* A1w = W1t + (size_t)g*32768 + (16*w)*512 + lane*8;
    short8 af[16];
#pragma unroll
    for (int i=0;i<16;++i) af[i] = *(const short8*)(A1w + i*512);
#pragma unroll
    for (int kc=0;kc<8;++kc){
      short8 bx[4];
#pragma unroll
      for (int rr=0;rr<4;++rr)
        bx[rr] = *(const short8*)(Xs + ((rr*8 + kc)*64 + lane)*8);
#pragma unroll
      for (int rr=0;rr<4;++rr){
        acc[rr][0] = MFMA16(af[kc],   bx[rr], acc[rr][0]);
        acc[rr][1] = MFMA16(af[8+kc], bx[rr], acc[rr][1]);
      }
    }
  }
  __syncthreads();                                  // B2: all X reads done
  {
    f32x4 bv0 = *(const f32x4*)(b1 + g*DD + 32*w + 4*lq);
    f32x4 bv1 = *(const f32x4*)(b1 + g*DD + 32*w + 16 + 4*lq);
#pragma unroll
    for (int rr=0;rr<4;++rr){
#pragma unroll
      for (int q=0;q<2;++q){
        f32x4 bv = q ? bv1 : bv0;
        short4v pk;
#pragma unroll
        for (int j=0;j<4;++j) pk[j] = f2bf(fmaxf(acc[rr][q][j] + bv[j], 0.f));
        *(short4v*)(Xs + ((rr*4 + w)*64 + (2*q + (lq>>1))*16 + l15)*8 + 4*(lq&1)) = pk;
      }
    }
  }
  __syncthreads();                                  // B3: H1 ready

  // ---- GEMM2: K=128, A preloaded (8 frags) ----
  f32x4 acc2[4][2];
#pragma unroll
  for (int rr=0;rr<4;++rr){ acc2[rr][0]=zf; acc2[rr][1]=zf; }
  {
    const short* A2w = W2t + (size_t)g*16384 + (8*w)*512 + lane*8;
    short8 af[8];
#pragma unroll
    for (int i=0;i<8;++i) af[i] = *(const short8*)(A2w + i*512);
#pragma unroll
    for (int kc=0;kc<4;++kc){
      short8 bx[4];
#pragma unroll
      for (int rr=0;rr<4;++rr)
        bx[rr] = *(const short8*)(Xs + ((rr*4 + kc)*64 + lane)*8);
#pragma unroll
      for (int rr=0;rr<4;++rr){
        acc2[rr][0] = MFMA16(af[kc],   bx[rr], acc2[rr][0]);
        acc2[rr][1] = MFMA16(af[4+kc], bx[rr], acc2[rr][1]);
      }
    }
  }
  // H2 -> Xs[8192:16384) (disjoint from H1; region dead since B2)
  {
    f32x4 bv0 = *(const f32x4*)(b2 + g*DD + 32*w + 4*lq);
    f32x4 bv1 = *(const f32x4*)(b2 + g*DD + 32*w + 16 + 4*lq);
#pragma unroll
    for (int rr=0;rr<4;++rr){
#pragma unroll
      for (int q=0;q<2;++q){
        f32x4 bv = q ? bv1 : bv0;
        short4v pk;
#pragma unroll
        for (int j=0;j<4;++j) pk[j] = f2bf(fmaxf(acc2[rr][q][j] + bv[j], 0.f));
        *(short4v*)(Xs + 8192 + ((rr*4 + w)*64 + (2*q + (lq>>1))*16 + l15)*8 + 4*(lq&1)) = pk;
      }
    }
  }
  __syncthreads();                                  // B4: H2 ready

  // ---- GEMM3: K=128, A preloaded (8 frags) ----
  f32x4 acc3[4][2];
#pragma unroll
  for (int rr=0;rr<4;++rr){ acc3[rr][0]=zf; acc3[rr][1]=zf; }
  {
    const short* A3w = W3t + (size_t)g*16384 + (8*w)*512 + lane*8;
    short8 af[8];
#pragma unroll
    for (int i=0;i<8;++i) af[i] = *(const short8*)(A3w + i*512);
#pragma unroll
    for (int kc=0;kc<4;++kc){
      short8 bx[4];
#pragma unroll
      for (int rr=0;rr<4;++rr)
        bx[rr] = *(const short8*)(Xs + 8192 + ((rr*4 + kc)*64 + lane)*8);
#pragma unroll
      for (int rr=0;rr<4;++rr){
        acc3[rr][0] = MFMA16(af[kc],   bx[rr], acc3[rr][0]);
        acc3[rr][1] = MFMA16(af[4+kc], bx[rr], acc3[rr][1]);
      }
    }
  }
  // pair-sum over F -> msg into Xs[0:4096)
  {
    f32x4 bv0 = *(const f32x4*)(b3 + g*DD + 32*w + 4*lq);
    f32x4 bv1 = *(const f32x4*)(b3 + g*DD + 32*w + 16 + 4*lq);
#pragma unroll
    for (int rr=0;rr<4;++rr){
#pragma unroll
      for (int q=0;q<2;++q){
        f32x4 bv = q ? bv1 : bv0;
        f32x4 mv;
#pragma unroll
        for (int j=0;j<4;++j){
          float v = acc3[rr][q][j];
          mv[j] = v + __shfl_xor(v, 1) + 2.f*bv[j];
        }
        if ((l15 & 1) == 0){
          int n = rr*8 + (l15>>1);                 // node 0..31
          short4v pk;
#pragma unroll
          for (int j=0;j<4;++j) pk[j] = f2bf(mv[j]);
          *(short4v*)(Xs + (((n>>4)*4 + w)*64 + (2*q + (lq>>1))*16 + (n&15))*8 + 4*(lq&1)) = pk;
        }
      }
    }
  }
  __syncthreads();                                  // B5: msg ready

  // ---- GRU: gi = msg(32x128) @ Wi[g]; h==0 so gh==bh. 2 q-passes, A preloaded ----
  const short* AW = Wit + (size_t)g*49152 + lane*8;
  const int lo = lvl*MM;
#pragma unroll
  for (int q=0;q<2;++q){
    short8 af[12];
#pragma unroll
    for (int kc=0;kc<4;++kc){
      int cti = ((2*w + q)*4 + kc)*512;
      af[kc]   = *(const short8*)(AW + cti);
      af[4+kc] = *(const short8*)(AW + 16384 + cti);
      af[8+kc] = *(const short8*)(AW + 32768 + cti);
    }
    f32x4 gr[2], gz[2], gn[2];
    gr[0]=zf; gr[1]=zf; gz[0]=zf; gz[1]=zf; gn[0]=zf; gn[1]=zf;
#pragma unroll
    for (int kc=0;kc<4;++kc){
#pragma unroll
      for (int rfm=0;rfm<2;++rfm){
        short8 bm = *(const short8*)(Xs + ((rfm*4 + kc)*64 + lane)*8);
        gr[rfm] = MFMA16(af[kc],   bm, gr[rfm]);
        gz[rfm] = MFMA16(af[4+kc], bm, gz[rfm]);
        gn[rfm] = MFMA16(af[8+kc], bm, gn[rfm]);
      }
    }
    int col = 32*w + 16*q + 4*lq;
    f32x4 biR = *(const f32x4*)(bi + g*384 + col);
    f32x4 biZ = *(const f32x4*)(bi + g*384 + 128 + col);
    f32x4 biN = *(const f32x4*)(bi + g*384 + 256 + col);
    f32x4 bhR = *(const f32x4*)(bh + g*384 + col);
    f32x4 bhZ = *(const f32x4*)(bh + g*384 + 128 + col);
    f32x4 bhN = *(const f32x4*)(bh + g*384 + 256 + col);
#pragma unroll
    for (int rfm=0;rfm<2;++rfm){
      int m = nodebuf[rfm*16 + l15];
      if (m < 0) continue;
      f32x4 o; short4v pk;
#pragma unroll
      for (int j=0;j<4;++j){
        float xr = gr[rfm][j] + biR[j] + bhR[j];
        float xz = gz[rfm][j] + biZ[j] + bhZ[j];
        float r_ = 1.f/(1.f + __expf(-xr));
        float z_ = 1.f/(1.f + __expf(-xz));
        float xn = gn[rfm][j] + biN[j] + r_*bhN[j];
        float n_ = 2.f/(1.f + __expf(-2.f*xn)) - 1.f;
        o[j] = (1.f - z_)*n_;
        pk[j] = f2bf(o[j]);
      }
      *(f32x4*)(hfg + (size_t)(lo + m)*DD + col) = o;
      *(short4v*)(hf_sh + (size_t)(lo + m)*DD + col) = pk;
    }
  }
}

extern "C" void kernel_launch(void* const* d_in, const int* in_sizes, int n_in,
                              void* d_out, int out_size, void* d_ws, size_t ws_size,
                              hipStream_t stream)
{
  const float* s    = (const float*)d_in[0];
  const float* t    = (const float*)d_in[1];
  const int*   gate = (const int*)d_in[2];
  const int*   fanin= (const int*)d_in[3];
  const float* hs_W = (const float*)d_in[4];
  const float* hs_b = (const float*)d_in[5];
  const float* W1   = (const float*)d_in[6];
  const float* b1   = (const float*)d_in[7];
  const float* W2   = (const float*)d_in[8];
  const float* b2   = (const float*)d_in[9];
  const float* W3   = (const float*)d_in[10];
  const float* b3   = (const float*)d_in[11];
  const float* Wi   = (const float*)d_in[12];
  // d_in[13] = gru_Wh: unused (hidden state is exactly zero)
  const float* bi   = (const float*)d_in[14];
  const float* bh   = (const float*)d_in[15];

  float* hs = (float*)d_out;
  float* hf = hs + (size_t)NN*DD;

  int* cnt    = (int*)d_ws;        // [7][5] ; cur right after
  int* cur    = cnt + 35;
  int* off    = cnt + 70;
  int* pendv  = cnt + 105;
  int* sorted = cnt + 256;         // 7*SORT_STRIDE ints, < 1 MB

  short* wbase = (short*)((char*)d_ws + (1<<20));
  short* hsWt = wbase;             // 4096*8
  short* W1t  = wbase + 32768;     // 5*32768
  short* W2t  = wbase + 196608;    // 5*16384
  short* W3t  = wbase + 278528;    // 5*16384
  short* Wit  = wbase + 360448;    // 5*49152

  short* hs_sh = (short*)((char*)d_ws + (size_t)(8<<20));   // [N][128] bf16
  short* hf_sh = hs_sh + (size_t)NN*DD;                      // [N][128] bf16

  prep_kernel<<<296, 256, 0, stream>>>(hs_W, W1, W2, W3, Wi,
                                       hsWt, W1t, W2t, W3t, Wit, cnt);
  count_kernel<<<896, 256, 0, stream>>>(gate, cnt);
  offs_kernel<<<1, 256, 0, stream>>>(cnt, off, pendv, sorted);
  scatter_kernel<<<896, 256, 0, stream>>>(gate, off, cur, sorted);
  hs_kernel<<<NN/64, 256, 0, stream>>>(s, t, hsWt, hs_b, hs, hs_sh, hf, hf_sh);
  for (int lvl = 1; lvl < LL; ++lvl){
    level_kernel<<<SORT_STRIDE/32, 256, 0, stream>>>(lvl, hf,
        hs_sh, hf_sh, fanin, W1t, W2t, W3t, Wit,
        b1, b2, b3, bi, bh, off, pendv, sorted);
  }
}

// Round 12
// 388.246 us; speedup vs baseline: 3.8688x; 1.0385x over previous
//
#include <hip/hip_runtime.h>
#include <hip/hip_bf16.h>

#define DD 128
#define LL 8
#define MM 32768
#define NN (LL*MM)
#define GG 5
#define FF 2
#define SORT_STRIDE 33408   // 32768 + headroom (>= 5*31 pad)

typedef __attribute__((ext_vector_type(8))) short short8;
typedef __attribute__((ext_vector_type(4))) short short4v;
typedef __attribute__((ext_vector_type(4))) float f32x4;

#define MFMA16(a,b,c) __builtin_amdgcn_mfma_f32_16x16x32_bf16((a),(b),(c),0,0,0)
// Pin load-issue order: compiler cannot sink loads past a memory-clobber asm.
#define VMEM_FENCE() asm volatile("s_waitcnt vmcnt(0)" ::: "memory")

__device__ __forceinline__ short f2bf(float x){
  __hip_bfloat16 h = __float2bfloat16(x);
  return *reinterpret_cast<short*>(&h);
}

__device__ __forceinline__ short8 pack8(f32x4 a, f32x4 b){
  short8 r;
  r[0]=f2bf(a[0]); r[1]=f2bf(a[1]); r[2]=f2bf(a[2]); r[3]=f2bf(a[3]);
  r[4]=f2bf(b[0]); r[5]=f2bf(b[1]); r[6]=f2bf(b[2]); r[7]=f2bf(b[3]);
  return r;
}

// ---------------- one-time weight convert to fragment-contiguous bf16 ------
// Layout per tensor: [g][ct][kc][lane][8]  (ct = 16-col tile, kc = 32-k tile)
// value[j] = W[k = kc*32 + 8*(lane>>4) + j][col = ct*16 + (lane&15)]
__global__ void prep_kernel(const float* __restrict__ hs_W, const float* __restrict__ W1,
                            const float* __restrict__ W2, const float* __restrict__ W3,
                            const float* __restrict__ Wi,
                            short* __restrict__ hsWt, short* __restrict__ W1t,
                            short* __restrict__ W2t, short* __restrict__ W3t,
                            short* __restrict__ Wit, int* __restrict__ cntcur)
{
  if (blockIdx.x == 0 && threadIdx.x < 70) cntcur[threadIdx.x] = 0;  // cnt[35]+cur[35]
  int u = blockIdx.x*256 + threadIdx.x;   // 75776 units of 8 k-elems
  const float* src; short* dst; int ldw;
  if (u < 4096){                                   // hsWt: ct8 kc8
    int i=u, ct=i>>9, kc=(i>>6)&7, ln=i&63;
    src = hs_W + (size_t)(kc*32 + 8*(ln>>4))*128 + ct*16 + (ln&15);
    dst = hsWt + (size_t)i*8; ldw=128;
  } else if (u < 24576){                           // W1t: 5 x (ct8 kc8)
    int v=u-4096, g=v>>12, i=v&4095, ct=i>>9, kc=(i>>6)&7, ln=i&63;
    src = W1 + (size_t)g*32768 + (size_t)(kc*32 + 8*(ln>>4))*128 + ct*16 + (ln&15);
    dst = W1t + (size_t)g*32768 + i*8; ldw=128;
  } else if (u < 34816){                           // W2t: 5 x (ct8 kc4)
    int v=u-24576, g=v>>11, i=v&2047, ct=i>>8, kc=(i>>6)&3, ln=i&63;
    src = W2 + (size_t)g*16384 + (size_t)(kc*32 + 8*(ln>>4))*128 + ct*16 + (ln&15);
    dst = W2t + (size_t)g*16384 + i*8; ldw=128;
  } else if (u < 45056){                           // W3t: 5 x (ct8 kc4)
    int v=u-34816, g=v>>11, i=v&2047, ct=i>>8, kc=(i>>6)&3, ln=i&63;
    src = W3 + (size_t)g*16384 + (size_t)(kc*32 + 8*(ln>>4))*128 + ct*16 + (ln&15);
    dst = W3t + (size_t)g*16384 + i*8; ldw=128;
  } else {                                         // Wit: 5 x (ct24 kc4)
    int v=u-45056, g=v/6144, i=v%6144, ct=i>>8, kc=(i>>6)&3, ln=i&63;
    src = Wi + (size_t)g*49152 + (size_t)(kc*32 + 8*(ln>>4))*384 + ct*16 + (ln&15);
    dst = Wit + (size_t)g*49152 + i*8; ldw=384;
  }
  short8 o;
#pragma unroll
  for (int j=0;j<8;++j) o[j] = f2bf(src[(size_t)j*ldw]);
  *(short8*)dst = o;
}

// ---------------- bucket sort by gate, per level ----------------
__global__ void count_kernel(const int* __restrict__ gate, int* __restrict__ cnt){
  __shared__ int lc[GG];
  const int li = blockIdx.x >> 7;
  const int m  = ((blockIdx.x & 127) << 8) + threadIdx.x;
  if (threadIdx.x < GG) lc[threadIdx.x] = 0;
  __syncthreads();
  int g = gate[(li+1)*MM + m];
  atomicAdd(&lc[g], 1);
  __syncthreads();
  if (threadIdx.x < GG && lc[threadIdx.x] > 0)
    atomicAdd(&cnt[li*GG + threadIdx.x], lc[threadIdx.x]);
}

// offsets (pad 32) + fill pad slots with -1
__global__ void offs_kernel(const int* __restrict__ cnt, int* __restrict__ off,
                            int* __restrict__ pend, int* __restrict__ sorted){
  __shared__ int se[35], sp[35];
  const int tid = threadIdx.x;
  if (tid < LL-1){
    int l = tid, o = 0;
    for (int g = 0; g < GG; ++g){
      off[l*GG+g] = o;
      int c = cnt[l*GG+g];
      pend[l*GG+g] = o + c;
      se[l*GG+g] = o + c;
      o += ((c + 31) >> 5) << 5;          // pad each bucket to 32
      sp[l*GG+g] = o;
    }
  }
  __syncthreads();
  for (int b = 0; b < 35; ++b){
    int l = b / GG;
    for (int i = se[b] + tid; i < sp[b]; i += 256)
      sorted[l*SORT_STRIDE + i] = -1;
  }
}

__global__ void scatter_kernel(const int* __restrict__ gate, const int* __restrict__ off,
                               int* __restrict__ cur, int* __restrict__ sorted){
  __shared__ int lc[GG];
  __shared__ int base[GG];
  const int li = blockIdx.x >> 7;
  const int m  = ((blockIdx.x & 127) << 8) + threadIdx.x;
  if (threadIdx.x < GG) lc[threadIdx.x] = 0;
  __syncthreads();
  int g = gate[(li+1)*MM + m];
  int p = atomicAdd(&lc[g], 1);
  __syncthreads();
  if (threadIdx.x < GG)
    base[threadIdx.x] = atomicAdd(&cur[li*GG + threadIdx.x], lc[threadIdx.x]);
  __syncthreads();
  sorted[li*SORT_STRIDE + off[li*GG+g] + base[g] + p] = m;
}

// ---------------- hs = [s|t] @ hs_W + hs_b  (+ level-0 hf zero-fill) -------
// LDS exactly 32KB -> 5 blocks/CU. Forced-batch VMEM. Nontemporal f32 streams.
__global__ __launch_bounds__(256,5) void hs_kernel(
    const float* __restrict__ s, const float* __restrict__ t,
    const short* __restrict__ Wt, const float* __restrict__ b,
    float* __restrict__ hs, short* __restrict__ hs_sh,
    float* __restrict__ hf, short* __restrict__ hf_sh)
{
  __shared__ __align__(16) short Xs[16384];      // 32768 B exactly
  const int tid=threadIdx.x, lane=tid&63, w=tid>>6;   // w = 0..3
  const int l15=lane&15, lq=lane>>4;
  const int row0 = blockIdx.x*64;

  // stage X rows into fragment layout — 16 nt loads pinned in flight
  {
    const int r = tid>>2, p = tid&3;
    const float* srow = s + (size_t)(row0+r)*DD;
    const float* trow = t + (size_t)(row0+r)*DD;
    const int rf = r>>4, rl = r&15;
    f32x4 va[16];
#pragma unroll
    for (int i=0;i<8;++i){
      int u = p + 4*i;
      const float* pp = (u<16) ? (srow + 8*u) : (trow + 8*(u-16));
      va[2*i]   = __builtin_nontemporal_load((const f32x4*)pp);
      va[2*i+1] = __builtin_nontemporal_load((const f32x4*)(pp+4));
    }
    VMEM_FENCE();
#pragma unroll
    for (int i=0;i<8;++i){
      int u = p + 4*i;
      short8 v = pack8(va[2*i], va[2*i+1]);
      *(short8*)(Xs + ((rf*8+(u>>2))*64 + (u&3)*16 + rl)*8) = v;
    }
  }

  // level-0 hf zero-fill (replaces memset nodes); f32 stream nontemporal
  if (row0 < MM){
    f32x4 zf4 = {0.f,0.f,0.f,0.f};
    short8 zs8 = {0,0,0,0,0,0,0,0};
    const size_t basei = (size_t)row0*DD;
    for (int i=tid; i<2048; i+=256)
      __builtin_nontemporal_store(zf4, (f32x4*)(hf + basei + i*4));
    for (int i=tid; i<1024; i+=256) *(short8*)(hf_sh + basei + i*8) = zs8;
  }
  __syncthreads();

  f32x4 zf = {0.f,0.f,0.f,0.f};
  // preload wave's 16 A-fragments, pinned batch
  const short* Aw = Wt + (16*w)*512 + lane*8;
  short8 af[16];
#pragma unroll
  for (int i=0;i<16;++i) af[i] = *(const short8*)(Aw + i*512);
  VMEM_FENCE();

  f32x4 acc[4][2];
#pragma unroll
  for (int rr=0;rr<4;++rr){ acc[rr][0]=zf; acc[rr][1]=zf; }
#pragma unroll
  for (int kc=0;kc<8;++kc){
    short8 bx[4];
#pragma unroll
    for (int rr=0;rr<4;++rr)
      bx[rr] = *(const short8*)(Xs + ((rr*8 + kc)*64 + lane)*8);
#pragma unroll
    for (int rr=0;rr<4;++rr){
      acc[rr][0] = MFMA16(af[kc],   bx[rr], acc[rr][0]);   // ct = 2w
      acc[rr][1] = MFMA16(af[8+kc], bx[rr], acc[rr][1]);   // ct = 2w+1
    }
  }

  f32x4 bv0 = *(const f32x4*)(b + 32*w + 4*lq);
  f32x4 bv1 = *(const f32x4*)(b + 32*w + 16 + 4*lq);
#pragma unroll
  for (int rr=0;rr<4;++rr){
    int row = row0 + rr*16 + l15;
#pragma unroll
    for (int q=0;q<2;++q){
      f32x4 bv = q ? bv1 : bv0;
      int col = 32*w + 16*q + 4*lq;
      f32x4 o; short4v pk;
#pragma unroll
      for (int j=0;j<4;++j){ o[j] = acc[rr][q][j] + bv[j]; pk[j] = f2bf(o[j]); }
      __builtin_nontemporal_store(o, (f32x4*)(hs + (size_t)row*DD + col));
      *(short4v*)(hs_sh + (size_t)row*DD + col) = pk;
    }
  }
}

// ---------------- fused per-level kernel: 32 nodes/block, col-split --------
// LDS exactly 32KB (no nodebuf/srcbuf/ginfo -> 5 blocks/CU -> 1044 items fit
// in ONE machine round of 1280 slots). All VMEM batches pinned with VMEM_FENCE.
__global__ __launch_bounds__(256,5) void level_kernel(
    int lvl, float* __restrict__ hfg,
    const short* __restrict__ hs_sh, short* __restrict__ hf_sh,
    const int* __restrict__ fanin,
    const short* __restrict__ W1t, const short* __restrict__ W2t,
    const short* __restrict__ W3t, const short* __restrict__ Wit,
    const float* __restrict__ b1, const float* __restrict__ b2,
    const float* __restrict__ b3, const float* __restrict__ bi,
    const float* __restrict__ bh,
    const int* __restrict__ off, const int* __restrict__ pend,
    const int* __restrict__ sorted)
{
  __shared__ __align__(16) short Xs[16384];      // 32768 B exactly
  const int tid=threadIdx.x, lane=tid&63, w=tid>>6;  // w = 0..3
  const int l15=lane&15, lq=lane>>4;
  const int li = lvl-1;
  const int pos0 = blockIdx.x*32;

  // block-uniform gate (per-thread compute; off/pend are L2-hot)
  int g = -1;
#pragma unroll
  for (int q=0;q<GG;++q)
    if (pos0 >= off[li*GG+q] && pos0 < pend[li*GG+q]) g = q;
  if (g < 0) return;                              // uniform

  // gather X rows into fragment layout; thread: row r=tid>>2, unit p=tid&3
  {
    const int r = tid>>2, p = tid&3;
    const int mg = sorted[li*SORT_STRIDE + pos0 + (r>>1)];
    const int src = (mg>=0) ? li*MM + fanin[((size_t)li*MM+mg)*FF + (r&1)] : 0;
    const short* hsrow = hs_sh + (size_t)src*DD;
    const short* hfrow = hf_sh + (size_t)src*DD;
    const int rf = r>>4, rl = r&15;
    short8 va[8];
#pragma unroll
    for (int i=0;i<8;++i){
      int u = p + 4*i;
      va[i] = *(const short8*)((u<16) ? (hsrow + 8*u) : (hfrow + 8*(u-16)));
    }
    VMEM_FENCE();
#pragma unroll
    for (int i=0;i<8;++i){
      int u = p + 4*i;
      *(short8*)(Xs + ((rf*8+(u>>2))*64 + (u&3)*16 + rl)*8) = va[i];
    }
  }
  __syncthreads();                                // B1

  f32x4 zf = {0.f,0.f,0.f,0.f};

  // ---- GEMM1: K=256, A preloaded+pinned (16 frags) ----
  f32x4 acc[4][2];
#pragma unroll
  for (int rr=0;rr<4;++rr){ acc[rr][0]=zf; acc[rr][1]=zf; }
  {
    const short* A1w = W1t + (size_t)g*32768 + (16*w)*512 + lane*8;
    short8 af[16];
#pragma unroll
    for (int i=0;i<16;++i) af[i] = *(const short8*)(A1w + i*512);
    VMEM_FENCE();
#pragma unroll
    for (int kc=0;kc<8;++kc){
      short8 bx[4];
#pragma unroll
      for (int rr=0;rr<4;++rr)
        bx[rr] = *(const short8*)(Xs + ((rr*8 + kc)*64 + lane)*8);
#pragma unroll
      for (int rr=0;rr<4;++rr){
        acc[rr][0] = MFMA16(af[kc],   bx[rr], acc[rr][0]);
        acc[rr][1] = MFMA16(af[8+kc], bx[rr], acc[rr][1]);
      }
    }
  }
  __syncthreads();                                // B2: all X reads done
  {
    f32x4 bv0 = *(const f32x4*)(b1 + g*DD + 32*w + 4*lq);
    f32x4 bv1 = *(const f32x4*)(b1 + g*DD + 32*w + 16 + 4*lq);
#pragma unroll
    for (int rr=0;rr<4;++rr){
#pragma unroll
      for (int q=0;q<2;++q){
        f32x4 bv = q ? bv1 : bv0;
        short4v pk;
#pragma unroll
        for (int j=0;j<4;++j) pk[j] = f2bf(fmaxf(acc[rr][q][j] + bv[j], 0.f));
        *(short4v*)(Xs + ((rr*4 + w)*64 + (2*q + (lq>>1))*16 + l15)*8 + 4*(lq&1)) = pk;
      }
    }
  }
  __syncthreads();                                // B3: H1 ready

  // ---- GEMM2: K=128, A preloaded+pinned (8 frags) ----
  f32x4 acc2[4][2];
#pragma unroll
  for (int rr=0;rr<4;++rr){ acc2[rr][0]=zf; acc2[rr][1]=zf; }
  {
    const short* A2w = W2t + (size_t)g*16384 + (8*w)*512 + lane*8;
    short8 af[8];
#pragma unroll
    for (int i=0;i<8;++i) af[i] = *(const short8*)(A2w + i*512);
    VMEM_FENCE();
#pragma unroll
    for (int kc=0;kc<4;++kc){
      short8 bx[4];
#pragma unroll
      for (int rr=0;rr<4;++rr)
        bx[rr] = *(const short8*)(Xs + ((rr*4 + kc)*64 + lane)*8);
#pragma unroll
      for (int rr=0;rr<4;++rr){
        acc2[rr][0] = MFMA16(af[kc],   bx[rr], acc2[rr][0]);
        acc2[rr][1] = MFMA16(af[4+kc], bx[rr], acc2[rr][1]);
      }
    }
  }
  // H2 -> Xs[8192:16384) (disjoint from H1; region dead since B2)
  {
    f32x4 bv0 = *(const f32x4*)(b2 + g*DD + 32*w + 4*lq);
    f32x4 bv1 = *(const f32x4*)(b2 + g*DD + 32*w + 16 + 4*lq);
#pragma unroll
    for (int rr=0;rr<4;++rr){
#pragma unroll
      for (int q=0;q<2;++q){
        f32x4 bv = q ? bv1 : bv0;
        short4v pk;
#pragma unroll
        for (int j=0;j<4;++j) pk[j] = f2bf(fmaxf(acc2[rr][q][j] + bv[j], 0.f));
        *(short4v*)(Xs + 8192 + ((rr*4 + w)*64 + (2*q + (lq>>1))*16 + l15)*8 + 4*(lq&1)) = pk;
      }
    }
  }
  __syncthreads();                                // B4: H2 ready

  // ---- GEMM3: K=128, A preloaded+pinned (8 frags) ----
  f32x4 acc3[4][2];
#pragma unroll
  for (int rr=0;rr<4;++rr){ acc3[rr][0]=zf; acc3[rr][1]=zf; }
  {
    const short* A3w = W3t + (size_t)g*16384 + (8*w)*512 + lane*8;
    short8 af[8];
#pragma unroll
    for (int i=0;i<8;++i) af[i] = *(const short8*)(A3w + i*512);
    VMEM_FENCE();
#pragma unroll
    for (int kc=0;kc<4;++kc){
      short8 bx[4];
#pragma unroll
      for (int rr=0;rr<4;++rr)
        bx[rr] = *(const short8*)(Xs + 8192 + ((rr*4 + kc)*64 + lane)*8);
#pragma unroll
      for (int rr=0;rr<4;++rr){
        acc3[rr][0] = MFMA16(af[kc],   bx[rr], acc3[rr][0]);
        acc3[rr][1] = MFMA16(af[4+kc], bx[rr], acc3[rr][1]);
      }
    }
  }
  // pair-sum over F -> msg into Xs[0:4096)
  {
    f32x4 bv0 = *(const f32x4*)(b3 + g*DD + 32*w + 4*lq);
    f32x4 bv1 = *(const f32x4*)(b3 + g*DD + 32*w + 16 + 4*lq);
#pragma unroll
    for (int rr=0;rr<4;++rr){
#pragma unroll
      for (int q=0;q<2;++q){
        f32x4 bv = q ? bv1 : bv0;
        f32x4 mv;
#pragma unroll
        for (int j=0;j<4;++j){
          float v = acc3[rr][q][j];
          mv[j] = v + __shfl_xor(v, 1) + 2.f*bv[j];
        }
        if ((l15 & 1) == 0){
          int n = rr*8 + (l15>>1);                 // node 0..31
          short4v pk;
#pragma unroll
          for (int j=0;j<4;++j) pk[j] = f2bf(mv[j]);
          *(short4v*)(Xs + (((n>>4)*4 + w)*64 + (2*q + (lq>>1))*16 + (n&15))*8 + 4*(lq&1)) = pk;
        }
      }
    }
  }
  __syncthreads();                                // B5: msg ready

  // ---- GRU: gi = msg(32x128) @ Wi[g]; h==0 so gh==bh. 2 q-passes ----
  const short* AW = Wit + (size_t)g*49152 + lane*8;
  const int lo = lvl*MM;
  const int m0 = sorted[li*SORT_STRIDE + pos0 + l15];
  const int m1 = sorted[li*SORT_STRIDE + pos0 + 16 + l15];
#pragma unroll
  for (int q=0;q<2;++q){
    short8 af[12];
#pragma unroll
    for (int kc=0;kc<4;++kc){
      int cti = ((2*w + q)*4 + kc)*512;
      af[kc]   = *(const short8*)(AW + cti);
      af[4+kc] = *(const short8*)(AW + 16384 + cti);
      af[8+kc] = *(const short8*)(AW + 32768 + cti);
    }
    VMEM_FENCE();
    f32x4 gr[2], gz[2], gn[2];
    gr[0]=zf; gr[1]=zf; gz[0]=zf; gz[1]=zf; gn[0]=zf; gn[1]=zf;
#pragma unroll
    for (int kc=0;kc<4;++kc){
#pragma unroll
      for (int rfm=0;rfm<2;++rfm){
        short8 bm = *(const short8*)(Xs + ((rfm*4 + kc)*64 + lane)*8);
        gr[rfm] = MFMA16(af[kc],   bm, gr[rfm]);
        gz[rfm] = MFMA16(af[4+kc], bm, gz[rfm]);
        gn[rfm] = MFMA16(af[8+kc], bm, gn[rfm]);
      }
    }
    int col = 32*w + 16*q + 4*lq;
    f32x4 biR = *(const f32x4*)(bi + g*384 + col);
    f32x4 biZ = *(const f32x4*)(bi + g*384 + 128 + col);
    f32x4 biN = *(const f32x4*)(bi + g*384 + 256 + col);
    f32x4 bhR = *(const f32x4*)(bh + g*384 + col);
    f32x4 bhZ = *(const f32x4*)(bh + g*384 + 128 + col);
    f32x4 bhN = *(const f32x4*)(bh + g*384 + 256 + col);
#pragma unroll
    for (int rfm=0;rfm<2;++rfm){
      int m = rfm ? m1 : m0;
      if (m < 0) continue;
      f32x4 o; short4v pk;
#pragma unroll
      for (int j=0;j<4;++j){
        float xr = gr[rfm][j] + biR[j] + bhR[j];
        float xz = gz[rfm][j] + biZ[j] + bhZ[j];
        float r_ = 1.f/(1.f + __expf(-xr));
        float z_ = 1.f/(1.f + __expf(-xz));
        float xn = gn[rfm][j] + biN[j] + r_*bhN[j];
        float n_ = 2.f/(1.f + __expf(-2.f*xn)) - 1.f;
        o[j] = (1.f - z_)*n_;
        pk[j] = f2bf(o[j]);
      }
      __builtin_nontemporal_store(o, (f32x4*)(hfg + (size_t)(lo + m)*DD + col));
      *(short4v*)(hf_sh + (size_t)(lo + m)*DD + col) = pk;
    }
  }
}

extern "C" void kernel_launch(void* const* d_in, const int* in_sizes, int n_in,
                              void* d_out, int out_size, void* d_ws, size_t ws_size,
                              hipStream_t stream)
{
  const float* s    = (const float*)d_in[0];
  const float* t    = (const float*)d_in[1];
  const int*   gate = (const int*)d_in[2];
  const int*   fanin= (const int*)d_in[3];
  const float* hs_W = (const float*)d_in[4];
  const float* hs_b = (const float*)d_in[5];
  const float* W1   = (const float*)d_in[6];
  const float* b1   = (const float*)d_in[7];
  const float* W2   = (const float*)d_in[8];
  const float* b2   = (const float*)d_in[9];
  const float* W3   = (const float*)d_in[10];
  const float* b3   = (const float*)d_in[11];
  const float* Wi   = (const float*)d_in[12];
  // d_in[13] = gru_Wh: unused (hidden state is exactly zero)
  const float* bi   = (const float*)d_in[14];
  const float* bh   = (const float*)d_in[15];

  float* hs = (float*)d_out;
  float* hf = hs + (size_t)NN*DD;

  int* cnt    = (int*)d_ws;        // [7][5] ; cur right after
  int* cur    = cnt + 35;
  int* off    = cnt + 70;
  int* pendv  = cnt + 105;
  int* sorted = cnt + 256;         // 7*SORT_STRIDE ints, < 1 MB

  short* wbase = (short*)((char*)d_ws + (1<<20));
  short* hsWt = wbase;             // 4096*8
  short* W1t  = wbase + 32768;     // 5*32768
  short* W2t  = wbase + 196608;    // 5*16384
  short* W3t  = wbase + 278528;    // 5*16384
  short* Wit  = wbase + 360448;    // 5*49152

  short* hs_sh = (short*)((char*)d_ws + (size_t)(8<<20));   // [N][128] bf16
  short* hf_sh = hs_sh + (size_t)NN*DD;                      // [N][128] bf16

  prep_kernel<<<296, 256, 0, stream>>>(hs_W, W1, W2, W3, Wi,
                                       hsWt, W1t, W2t, W3t, Wit, cnt);
  count_kernel<<<896, 256, 0, stream>>>(gate, cnt);
  offs_kernel<<<1, 256, 0, stream>>>(cnt, off, pendv, sorted);
  scatter_kernel<<<896, 256, 0, stream>>>(gate, off, cur, sorted);
  hs_kernel<<<NN/64, 256, 0, stream>>>(s, t, hsWt, hs_b, hs, hs_sh, hf, hf_sh);
  for (int lvl = 1; lvl < LL; ++lvl){
    level_kernel<<<SORT_STRIDE/32, 256, 0, stream>>>(lvl, hf,
        hs_sh, hf_sh, fanin, W1t, W2t, W3t, Wit,
        b1, b2, b3, bi, bh, off, pendv, sorted);
  }
}